// Round 1
// baseline (1298.439 us; speedup 1.0000x reference)
//
#include <hip/hip_runtime.h>
#include <math.h>
#include <stdint.h>

#define EPSQ 1e-5f
#define WELEM 262144          // 512*512
#define OUT0N 2097152         // 4*1024*512
#define NRA   32768           // B*H*S rows of scores

// ---- workspace byte offsets ----
#define O_WSUM   0                       // float[4]  sum(W)
#define O_WABS   16                      // float[4]  sum|W|
#define O_MN     32                      // int       global-min bits
#define O_COLSUM 64                      // int[2048] colsum of kv per (bh,dd)
#define O_SIGNS  16384                   // int8[4*262144]
#define O_KQ     (O_SIGNS + 4*WELEM)     // int8[32768*64]
#define O_KK     (O_KQ + 2097152)
#define O_KV     (O_KK + 2097152)
#define O_RMAX   (O_KV + 2097152)        // float[32768]
#define O_RSUM   (O_RMAX + 131072)       // float[32768]
#define O_CTXQ   (O_RSUM + 131072)       // int8[2097152]  sig8 levels, view layout
#define O_OUTB   (O_CTXQ + 2097152)      // float[2097152] out before LN

__device__ __forceinline__ float clampf(float x, float lo, float hi) {
  return fminf(fmaxf(x, lo), hi);
}

// ---------------- init: zero accumulators, FLT_MAX min slot ----------------
__global__ void k_init(float* wsum, float* wabs, int* mn, int* colsum) {
  int t = threadIdx.x;
  if (t < 4) { wsum[t] = 0.f; wabs[t] = 0.f; }
  if (t == 4) *mn = 0x7F7FFFFF;  // +FLT_MAX bits
  for (int i = t; i < 2048; i += 256) colsum[i] = 0;
}

// ---------------- weight stats: sum, sum|.| per weight ----------------
__global__ void k_wstats(const float* Wq, const float* Wk, const float* Wv, const float* Wo,
                         float* wsum, float* wabs) {
  __shared__ float s1[256], s2[256];
  int w = blockIdx.x >> 6;
  const float* W = (w == 0) ? Wq : (w == 1) ? Wk : (w == 2) ? Wv : Wo;
  int base = (blockIdx.x & 63) * 4096;
  float s = 0.f, sa = 0.f;
  for (int i = threadIdx.x; i < 4096; i += 256) {
    float x = W[base + i];
    s += x; sa += fabsf(x);
  }
  s1[threadIdx.x] = s; s2[threadIdx.x] = sa; __syncthreads();
  for (int o = 128; o > 0; o >>= 1) {
    if (threadIdx.x < o) { s1[threadIdx.x] += s1[threadIdx.x + o]; s2[threadIdx.x] += s2[threadIdx.x + o]; }
    __syncthreads();
  }
  if (threadIdx.x == 0) { atomicAdd(&wsum[w], s1[0]); atomicAdd(&wabs[w], s2[0]); }
}

// ---------------- binarize: sign(W - e) ----------------
__global__ void k_sign(const float* Wq, const float* Wk, const float* Wv, const float* Wo,
                       const float* wsum, int8_t* signs) {
  int idx = blockIdx.x * 256 + threadIdx.x;
  int w = idx >> 18;
  int pos = idx & (WELEM - 1);
  const float* W = (w == 0) ? Wq : (w == 1) ? Wk : (w == 2) ? Wv : Wo;
  float e = wsum[w] * (1.0f / 262144.0f);
  float x = W[pos];
  signs[idx] = (int8_t)((x > e) - (x < e));
}

// ---------------- projection GEMM + head quant -> int8 [B,H,S,64] ----------------
__global__ __launch_bounds__(256) void k_proj(
    const float* q, const float* kin, const float* vin,
    const float* bq, const float* bk, const float* bv,
    const float* aq, const float* ak, const float* av,
    const float* acq, const float* ack, const float* acv,
    const int8_t* signs, const float* wabs,
    int8_t* kqo, int8_t* kko, int8_t* kvo) {
  __shared__ __align__(16) float As[32][68];
  __shared__ __align__(16) float Bs[32][68];
  int z = blockIdx.z;
  const float* X    = (z == 0) ? q   : (z == 1) ? kin : vin;
  const float* bias = (z == 0) ? bq  : (z == 1) ? bk  : bv;
  const float* aip  = (z == 0) ? aq  : (z == 1) ? ak  : av;
  const float* ahp  = (z == 0) ? acq : (z == 1) ? ack : acv;
  int8_t* outp      = (z == 0) ? kqo : (z == 1) ? kko : kvo;
  float a_in = fmaxf(aip[0], EPSQ);
  float a_hd = fmaxf(ahp[0], EPSQ);
  float m_w  = wabs[z] * (1.0f / 262144.0f);
  const int8_t* S = signs + (size_t)z * WELEM;

  int n0 = blockIdx.x * 64;
  int f0 = blockIdx.y * 64;
  int t = threadIdx.x;
  int tx = t & 15, ty = t >> 4;
  float acc[4][4] = {};
  for (int k0 = 0; k0 < 512; k0 += 32) {
#pragma unroll
    for (int i = 0; i < 8; ++i) {  // A: quantize activations on the fly
      int idx = t + i * 256;
      int kk = idx & 31, m = idx >> 5;
      float x = X[(size_t)(n0 + m) * 512 + k0 + kk];
      As[kk][m] = clampf(rintf(x / a_in), -8.f, 7.f);
    }
#pragma unroll
    for (int i = 0; i < 8; ++i) {  // B: weight signs
      int idx = t + i * 256;
      int kk = idx & 31, n = idx >> 5;
      Bs[kk][n] = (float)S[(size_t)(f0 + n) * 512 + k0 + kk];
    }
    __syncthreads();
#pragma unroll
    for (int kk = 0; kk < 32; ++kk) {
      float4 a4 = *(const float4*)&As[kk][ty * 4];
      float4 b4 = *(const float4*)&Bs[kk][tx * 4];
      float aa[4] = {a4.x, a4.y, a4.z, a4.w};
      float bb[4] = {b4.x, b4.y, b4.z, b4.w};
#pragma unroll
      for (int i = 0; i < 4; ++i)
#pragma unroll
        for (int j = 0; j < 4; ++j) acc[i][j] += aa[i] * bb[j];
    }
    __syncthreads();
  }
  float s_am = a_in * m_w;
#pragma unroll
  for (int i = 0; i < 4; ++i) {
    int n = n0 + ty * 4 + i;
    int b = n >> 10, srow = n & 1023;
#pragma unroll
    for (int j = 0; j < 4; ++j) {
      int f = f0 + tx * 4 + j;
      float P = s_am * acc[i][j] + bias[f];
      float hq = clampf(rintf(P / a_hd), -8.f, 7.f);
      int h = f >> 6, dd = f & 63;
      outp[(size_t)((b * 8 + h) * 1024 + srow) * 64 + dd] = (int8_t)hq;
    }
  }
}

// ---------------- column sums of kv per (bh, dd) ----------------
__global__ void k_colsum(const int8_t* kv, int* colsum) {
  __shared__ int red[256];
  int bh = blockIdx.x;
  int t = threadIdx.x;
  int dd = t & 63, part = t >> 6;
  const int8_t* p = kv + (size_t)bh * 65536;
  int acc = 0;
  for (int s = part * 256; s < part * 256 + 256; ++s) acc += p[s * 64 + dd];
  red[t] = acc; __syncthreads();
  if (part == 0) colsum[bh * 64 + dd] = red[dd] + red[64 + dd] + red[128 + dd] + red[192 + dd];
}

// ---------------- QK^T int GEMM -> scores (output 1) ----------------
__global__ __launch_bounds__(256) void k_qk(
    const int8_t* kq, const int8_t* kkv,
    const float* acq, const float* ack, float* scores) {
  __shared__ __align__(16) float As[64][68];
  __shared__ __align__(16) float Bs[64][68];
  int bh = blockIdx.z;
  int q0 = blockIdx.x * 64, c0 = blockIdx.y * 64;
  const int8_t* A  = kq  + (size_t)bh * 65536;
  const int8_t* Bp = kkv + (size_t)bh * 65536;
  int t = threadIdx.x;
#pragma unroll
  for (int i = 0; i < 16; ++i) {
    int idx = t + i * 256;
    int d = idx & 63, m = idx >> 6;
    As[d][m] = (float)A[(q0 + m) * 64 + d];
    Bs[d][m] = (float)Bp[(c0 + m) * 64 + d];
  }
  __syncthreads();
  int tx = t & 15, ty = t >> 4;
  float acc[4][4] = {};
#pragma unroll
  for (int d = 0; d < 64; ++d) {
    float4 a4 = *(const float4*)&As[d][ty * 4];
    float4 b4 = *(const float4*)&Bs[d][tx * 4];
    float aa[4] = {a4.x, a4.y, a4.z, a4.w};
    float bb[4] = {b4.x, b4.y, b4.z, b4.w};
#pragma unroll
    for (int i = 0; i < 4; ++i)
#pragma unroll
      for (int j = 0; j < 4; ++j) acc[i][j] += aa[i] * bb[j];
  }
  float sc = fmaxf(acq[0], EPSQ) * fmaxf(ack[0], EPSQ) * 0.125f;  // /sqrt(64)
#pragma unroll
  for (int i = 0; i < 4; ++i) {
    int qr = q0 + ty * 4 + i;
    float4 o = make_float4(sc * acc[i][0], sc * acc[i][1], sc * acc[i][2], sc * acc[i][3]);
    *(float4*)&scores[((size_t)bh * 1024 + qr) * 1024 + c0 + tx * 4] = o;
  }
}

// ---------------- per-row max / sumexp / global min(attn) ----------------
__global__ __launch_bounds__(256) void k_rowstats(
    const float* scores, float* rmax, float* rsum, int* mnbits) {
  __shared__ float red[256];
  int r = blockIdx.x, t = threadIdx.x;
  const float* p = scores + (size_t)r * 1024;
  float x0 = p[t], x1 = p[t + 256], x2 = p[t + 512], x3 = p[t + 768];
  float mx = fmaxf(fmaxf(x0, x1), fmaxf(x2, x3));
  red[t] = mx; __syncthreads();
  for (int o = 128; o > 0; o >>= 1) { if (t < o) red[t] = fmaxf(red[t], red[t + o]); __syncthreads(); }
  float rowmax = red[0]; __syncthreads();
  float se = expf(x0 - rowmax) + expf(x1 - rowmax) + expf(x2 - rowmax) + expf(x3 - rowmax);
  red[t] = se; __syncthreads();
  for (int o = 128; o > 0; o >>= 1) { if (t < o) red[t] += red[t + o]; __syncthreads(); }
  float rowsum = red[0]; __syncthreads();
  float mn4 = fminf(fminf(x0, x1), fminf(x2, x3));
  red[t] = mn4; __syncthreads();
  for (int o = 128; o > 0; o >>= 1) { if (t < o) red[t] = fminf(red[t], red[t + o]); __syncthreads(); }
  if (t == 0) {
    rmax[r] = rowmax; rsum[r] = rowsum;
    // min(attn) in this row, computed with the SAME expression as k_pv
    float cand = expf(red[0] - rowmax) / rowsum;
    atomicMin(mnbits, __float_as_int(cand));  // positive floats: int order == float order
  }
}

// ---------------- softmax + uns4 + PV int GEMM + sig8 -> ctxq (view layout) --------
__global__ __launch_bounds__(256) void k_pv(
    const float* scores, const float* rmax, const float* rsum,
    const int* mnbits, const int* colsum, const int8_t* kv,
    const float* acattn, const float* acv, const float* ao,
    int8_t* ctxq) {
  __shared__ __align__(16) float As[64][68];
  __shared__ __align__(16) float Bs[64][68];
  int bh = blockIdx.y;
  int m0 = blockIdx.x * 64;
  float mn = __int_as_float(*mnbits);
  float a_att = fmaxf(acattn[0], EPSQ);
  float a_v   = fmaxf(acv[0], EPSQ);
  float a_o   = fmaxf(ao[0], EPSQ);
  const float* Sp = scores + (size_t)bh * 1048576;
  const int8_t* Vp = kv + (size_t)bh * 65536;
  int t = threadIdx.x;
  int tx = t & 15, ty = t >> 4;
  float acc[4][4] = {};
  for (int k0 = 0; k0 < 1024; k0 += 64) {
#pragma unroll
    for (int i = 0; i < 16; ++i) {  // A: attn levels u in [0,15]
      int idx = t + i * 256;
      int c = idx & 63, m = idx >> 6;
      int r = bh * 1024 + m0 + m;
      float s = Sp[(size_t)(m0 + m) * 1024 + k0 + c];
      float attn = expf(s - rmax[r]) / rsum[r];
      As[c][m] = clampf(rintf((attn - mn) / a_att), 0.f, 15.f);
    }
#pragma unroll
    for (int i = 0; i < 16; ++i) {  // B: V levels
      int idx = t + i * 256;
      int dd = idx & 63, c = idx >> 6;
      Bs[c][dd] = (float)Vp[(size_t)(k0 + c) * 64 + dd];
    }
    __syncthreads();
#pragma unroll
    for (int c = 0; c < 64; ++c) {
      float4 a4 = *(const float4*)&As[c][ty * 4];
      float4 b4 = *(const float4*)&Bs[c][tx * 4];
      float aa[4] = {a4.x, a4.y, a4.z, a4.w};
      float bb[4] = {b4.x, b4.y, b4.z, b4.w};
#pragma unroll
      for (int i = 0; i < 4; ++i)
#pragma unroll
        for (int j = 0; j < 4; ++j) acc[i][j] += aa[i] * bb[j];
    }
    __syncthreads();
  }
  // ctx = a_att*a_v * (u.kv) + mn*a_v * colsum(kv);  sig8 levels in the faithful view layout
  float sc = a_att * a_v;
  float mnv = mn * a_v;
  int b = bh >> 3, h = bh & 7;
#pragma unroll
  for (int j = 0; j < 4; ++j) {
    int dd = tx * 4 + j;
    float cs = (float)colsum[bh * 64 + dd];
#pragma unroll
    for (int i = 0; i < 4; ++i) {
      int srow = m0 + ty * 4 + i;
      float ctx = sc * acc[i][j] + mnv * cs;
      float c8 = clampf(rintf(ctx / a_o), -128.f, 127.f);
      // ctx[b,h,s,dd] -> view[b, h*128 + s/8, (s%8)*64 + dd]
      ctxq[(size_t)b * 524288 + (size_t)(h * 128 + (srow >> 3)) * 512 + (srow & 7) * 64 + dd] = (int8_t)c8;
    }
  }
}

// ---------------- output projection int GEMM ----------------
__global__ __launch_bounds__(256) void k_outg(
    const int8_t* ctxq, const int8_t* signs_o,
    const float* wabs, const float* ao, float* outb) {
  __shared__ __align__(16) float As[32][68];
  __shared__ __align__(16) float Bs[32][68];
  int n0 = blockIdx.x * 64, f0 = blockIdx.y * 64;
  int t = threadIdx.x, tx = t & 15, ty = t >> 4;
  float acc[4][4] = {};
  for (int k0 = 0; k0 < 512; k0 += 32) {
#pragma unroll
    for (int i = 0; i < 8; ++i) {
      int idx = t + i * 256;
      int kk = idx & 31, m = idx >> 5;
      As[kk][m] = (float)ctxq[(size_t)(n0 + m) * 512 + k0 + kk];
      Bs[kk][m] = (float)signs_o[(size_t)(f0 + m) * 512 + k0 + kk];
    }
    __syncthreads();
#pragma unroll
    for (int kk = 0; kk < 32; ++kk) {
      float4 a4 = *(const float4*)&As[kk][ty * 4];
      float4 b4 = *(const float4*)&Bs[kk][tx * 4];
      float aa[4] = {a4.x, a4.y, a4.z, a4.w};
      float bb[4] = {b4.x, b4.y, b4.z, b4.w};
#pragma unroll
      for (int i = 0; i < 4; ++i)
#pragma unroll
        for (int j = 0; j < 4; ++j) acc[i][j] += aa[i] * bb[j];
    }
    __syncthreads();
  }
  float scale = fmaxf(ao[0], EPSQ) * (wabs[3] * (1.0f / 262144.0f));
#pragma unroll
  for (int i = 0; i < 4; ++i)
#pragma unroll
    for (int j = 0; j < 4; ++j)
      outb[(size_t)(n0 + ty * 4 + i) * 512 + f0 + tx * 4 + j] = scale * acc[i][j];
}

// ---------------- layernorm(q + out) -> output 0 ----------------
__global__ __launch_bounds__(256) void k_ln(
    const float* q, const float* outb, const float* g, const float* bb, float* out0) {
  __shared__ float red[256];
  int r = blockIdx.x, t = threadIdx.x;
  const float* qp = q + (size_t)r * 512;
  const float* op = outb + (size_t)r * 512;
  float y0 = qp[t] + op[t];
  float y1 = qp[t + 256] + op[t + 256];
  red[t] = y0 + y1; __syncthreads();
  for (int o = 128; o > 0; o >>= 1) { if (t < o) red[t] += red[t + o]; __syncthreads(); }
  float mu = red[0] * (1.0f / 512.0f); __syncthreads();
  float d0 = y0 - mu, d1 = y1 - mu;
  red[t] = d0 * d0 + d1 * d1; __syncthreads();
  for (int o = 128; o > 0; o >>= 1) { if (t < o) red[t] += red[t + o]; __syncthreads(); }
  float var = red[0] * (1.0f / 512.0f);
  float den = sqrtf(var + 1e-5f);
  out0[(size_t)r * 512 + t]       = d0 / den * g[t] + bb[t];
  out0[(size_t)r * 512 + t + 256] = d1 / den * g[t + 256] + bb[t + 256];
}

extern "C" void kernel_launch(void* const* d_in, const int* in_sizes, int n_in,
                              void* d_out, int out_size, void* d_ws, size_t ws_size,
                              hipStream_t stream) {
  const float* q   = (const float*)d_in[0];
  const float* k   = (const float*)d_in[1];
  const float* v   = (const float*)d_in[2];
  // d_in[3] = mask (int32) — structurally unused by the reference
  const float* Wq  = (const float*)d_in[4];
  const float* Wk  = (const float*)d_in[5];
  const float* Wv  = (const float*)d_in[6];
  const float* Wo  = (const float*)d_in[7];
  const float* bq  = (const float*)d_in[8];
  const float* bk  = (const float*)d_in[9];
  const float* bv  = (const float*)d_in[10];
  const float* lng = (const float*)d_in[11];
  const float* lnb = (const float*)d_in[12];
  const float* aq  = (const float*)d_in[13];
  const float* ak  = (const float*)d_in[14];
  const float* av  = (const float*)d_in[15];
  const float* acq = (const float*)d_in[16];
  const float* ack = (const float*)d_in[17];
  const float* acv = (const float*)d_in[18];
  const float* aca = (const float*)d_in[19];
  const float* ao  = (const float*)d_in[20];

  char* ws = (char*)d_ws;
  float* wsum   = (float*)(ws + O_WSUM);
  float* wabs   = (float*)(ws + O_WABS);
  int*   mnb    = (int*)(ws + O_MN);
  int*   colsum = (int*)(ws + O_COLSUM);
  int8_t* signs = (int8_t*)(ws + O_SIGNS);
  int8_t* kqb   = (int8_t*)(ws + O_KQ);
  int8_t* kkb   = (int8_t*)(ws + O_KK);
  int8_t* kvb   = (int8_t*)(ws + O_KV);
  float* rmax   = (float*)(ws + O_RMAX);
  float* rsum   = (float*)(ws + O_RSUM);
  int8_t* ctxq  = (int8_t*)(ws + O_CTXQ);
  float* outb   = (float*)(ws + O_OUTB);

  float* out0   = (float*)d_out;
  float* scores = (float*)d_out + OUT0N;

  k_init<<<1, 256, 0, stream>>>(wsum, wabs, mnb, colsum);
  k_wstats<<<256, 256, 0, stream>>>(Wq, Wk, Wv, Wo, wsum, wabs);
  k_sign<<<4096, 256, 0, stream>>>(Wq, Wk, Wv, Wo, wsum, signs);
  k_proj<<<dim3(64, 8, 3), 256, 0, stream>>>(q, k, v, bq, bk, bv, aq, ak, av,
                                             acq, ack, acv, signs, wabs, kqb, kkb, kvb);
  k_colsum<<<32, 256, 0, stream>>>(kvb, colsum);
  k_qk<<<dim3(16, 16, 32), 256, 0, stream>>>(kqb, kkb, acq, ack, scores);
  k_rowstats<<<32768, 256, 0, stream>>>(scores, rmax, rsum, mnb);
  k_pv<<<dim3(16, 32), 256, 0, stream>>>(scores, rmax, rsum, mnb, colsum, kvb,
                                         aca, acv, ao, ctxq);
  k_outg<<<dim3(64, 8), 256, 0, stream>>>(ctxq, signs, wabs, ao, outb);
  k_ln<<<4096, 256, 0, stream>>>(q, outb, lng, lnb, out0);
}

// Round 2
// 998.415 us; speedup vs baseline: 1.3005x; 1.3005x over previous
//
#include <hip/hip_runtime.h>
#include <math.h>
#include <stdint.h>

#define EPSQ 1e-5f
#define WELEM 262144          // 512*512
#define OUT0N 2097152         // 4*1024*512

// ---- workspace byte offsets ----
#define O_WSUM   0                       // float[4]  sum(W)
#define O_WABS   16                      // float[4]  sum|W|
#define O_MN     32                      // int       global-min bits
#define O_COLSUM 64                      // int[2048] colsum of kv per (bh,dd)
#define O_SIGNS  16384                   // int8[4*262144]
#define O_KQ     (O_SIGNS + 4*WELEM)     // int8[32*1024*64] per-head q levels
#define O_KK     (O_KQ + 2097152)
#define O_KV     (O_KK + 2097152)
#define O_VT     (O_KV + 2097152)        // int8[32][64][1024] V transposed
#define O_RMAX   (O_VT + 2097152)        // float[32768]
#define O_RSUM   (O_RMAX + 131072)       // float[32768]
#define O_CTXQ   (O_RSUM + 131072)       // int8[2097152]  sig8 levels, view layout
#define O_OUTB   (O_CTXQ + 2097152)      // float[2097152] out before LN

#define AS 72  // LDS row stride in bf16 elems: 144 B, 16B-aligned, conflict-benign

typedef __bf16 bf16x8 __attribute__((ext_vector_type(8)));
typedef float  floatx4 __attribute__((ext_vector_type(4)));

__device__ __forceinline__ float clampf(float x, float lo, float hi) {
  return fminf(fmaxf(x, lo), hi);
}

// ---------------- init ----------------
__global__ void k_init(float* wsum, float* wabs, int* mn, int* colsum) {
  int t = threadIdx.x;
  if (t < 4) { wsum[t] = 0.f; wabs[t] = 0.f; }
  if (t == 4) *mn = 0x7F7FFFFF;  // +FLT_MAX bits
  for (int i = t; i < 2048; i += 256) colsum[i] = 0;
}

// ---------------- weight stats ----------------
__global__ void k_wstats(const float* Wq, const float* Wk, const float* Wv, const float* Wo,
                         float* wsum, float* wabs) {
  __shared__ float s1[256], s2[256];
  int w = blockIdx.x >> 6;
  const float* W = (w == 0) ? Wq : (w == 1) ? Wk : (w == 2) ? Wv : Wo;
  int base = (blockIdx.x & 63) * 4096;
  float s = 0.f, sa = 0.f;
  for (int i = threadIdx.x; i < 4096; i += 256) {
    float x = W[base + i];
    s += x; sa += fabsf(x);
  }
  s1[threadIdx.x] = s; s2[threadIdx.x] = sa; __syncthreads();
  for (int o = 128; o > 0; o >>= 1) {
    if (threadIdx.x < o) { s1[threadIdx.x] += s1[threadIdx.x + o]; s2[threadIdx.x] += s2[threadIdx.x + o]; }
    __syncthreads();
  }
  if (threadIdx.x == 0) { atomicAdd(&wsum[w], s1[0]); atomicAdd(&wabs[w], s2[0]); }
}

// ---------------- binarize ----------------
__global__ void k_sign(const float* Wq, const float* Wk, const float* Wv, const float* Wo,
                       const float* wsum, int8_t* signs) {
  int idx = blockIdx.x * 256 + threadIdx.x;
  int w = idx >> 18;
  int pos = idx & (WELEM - 1);
  const float* W = (w == 0) ? Wq : (w == 1) ? Wk : (w == 2) ? Wv : Wo;
  float e = wsum[w] * (1.0f / 262144.0f);
  float x = W[pos];
  signs[idx] = (int8_t)((x > e) - (x < e));
}

// ---------------- projection: MFMA int-exact bf16 GEMM + head quant ----------------
__global__ __launch_bounds__(256) void k_proj(
    const float* q, const float* kin, const float* vin,
    const float* bq, const float* bk, const float* bv,
    const float* aq, const float* ak, const float* av,
    const float* acq, const float* ack, const float* acv,
    const int8_t* signs, const float* wabs,
    int8_t* kqo, int8_t* kko, int8_t* kvo) {
  __shared__ __align__(16) __bf16 As[64][AS];
  __shared__ __align__(16) __bf16 Bs[64][AS];
  int z = blockIdx.z;
  const float* X    = (z == 0) ? q   : (z == 1) ? kin : vin;
  const float* bias = (z == 0) ? bq  : (z == 1) ? bk  : bv;
  const float* aip  = (z == 0) ? aq  : (z == 1) ? ak  : av;
  const float* ahp  = (z == 0) ? acq : (z == 1) ? ack : acv;
  int8_t* outp      = (z == 0) ? kqo : (z == 1) ? kko : kvo;
  float a_in = fmaxf(aip[0], EPSQ);
  float a_hd = fmaxf(ahp[0], EPSQ);
  float m_w  = wabs[z] * (1.0f / 262144.0f);
  const int8_t* S = signs + (size_t)z * WELEM;

  int n0 = blockIdx.x * 64;
  int f0 = blockIdx.y * 64;
  int t = threadIdx.x;
  int lane = t & 63, w = t >> 6, quad = lane >> 4, l16 = lane & 15;
  floatx4 acc[4];
#pragma unroll
  for (int nt = 0; nt < 4; ++nt) acc[nt] = (floatx4){0.f, 0.f, 0.f, 0.f};

  for (int k0 = 0; k0 < 512; k0 += 64) {
#pragma unroll
    for (int i = 0; i < 16; ++i) {
      int idx = t + i * 256;
      int kk = idx & 63, m = idx >> 6;
      float x = X[(size_t)(n0 + m) * 512 + k0 + kk];
      As[m][kk] = (__bf16)clampf(rintf(x / a_in), -8.f, 7.f);
      Bs[m][kk] = (__bf16)(float)S[(size_t)(f0 + m) * 512 + k0 + kk];
    }
    __syncthreads();
#pragma unroll
    for (int kh = 0; kh < 64; kh += 32) {
      bf16x8 a = *(const bf16x8*)&As[w * 16 + l16][kh + quad * 8];
#pragma unroll
      for (int nt = 0; nt < 4; ++nt) {
        bf16x8 b = *(const bf16x8*)&Bs[nt * 16 + l16][kh + quad * 8];
        acc[nt] = __builtin_amdgcn_mfma_f32_16x16x32_bf16(a, b, acc[nt], 0, 0, 0);
      }
    }
    __syncthreads();
  }
  float s_am = a_in * m_w;
#pragma unroll
  for (int nt = 0; nt < 4; ++nt) {
    int f = f0 + nt * 16 + l16;
    int h = f >> 6, dd = f & 63;
    float bia = bias[f];
#pragma unroll
    for (int r = 0; r < 4; ++r) {
      int n = n0 + w * 16 + quad * 4 + r;
      int b = n >> 10, srow = n & 1023;
      float P = s_am * acc[nt][r] + bia;
      float hq = clampf(rintf(P / a_hd), -8.f, 7.f);
      outp[(size_t)((b * 8 + h) * 1024 + srow) * 64 + dd] = (int8_t)hq;
    }
  }
}

// ---------------- V transpose + column sums ----------------
__global__ __launch_bounds__(256) void k_vt(const int8_t* kv, int8_t* vt, int* colsum) {
  __shared__ int red[256];
  int bh = blockIdx.x;
  int t = threadIdx.x;
  int dd = t & 63, part = t >> 6;
  const int8_t* p = kv + (size_t)bh * 65536;
  int8_t* o = vt + (size_t)bh * 65536;
  int acc = 0;
  for (int s = part * 256; s < part * 256 + 256; ++s) {
    int8_t val = p[s * 64 + dd];
    o[dd * 1024 + s] = val;
    acc += val;
  }
  red[t] = acc; __syncthreads();
  if (part == 0) colsum[bh * 64 + dd] = red[dd] + red[64 + dd] + red[128 + dd] + red[192 + dd];
}

// ---------------- QK^T MFMA -> scores (output 1) ----------------
__global__ __launch_bounds__(256) void k_qk(
    const int8_t* kq, const int8_t* kkv,
    const float* acq, const float* ack, float* scores) {
  __shared__ __align__(16) __bf16 As[64][AS];
  __shared__ __align__(16) __bf16 Bs[64][AS];
  int bh = blockIdx.z;
  int q0 = blockIdx.x * 64, c0 = blockIdx.y * 64;
  const int8_t* A  = kq  + (size_t)bh * 65536;
  const int8_t* Bp = kkv + (size_t)bh * 65536;
  int t = threadIdx.x;
#pragma unroll
  for (int i = 0; i < 16; ++i) {
    int idx = t + i * 256;
    int d = idx & 63, m = idx >> 6;
    As[m][d] = (__bf16)(float)A[(q0 + m) * 64 + d];
    Bs[m][d] = (__bf16)(float)Bp[(c0 + m) * 64 + d];
  }
  __syncthreads();
  int lane = t & 63, w = t >> 6, quad = lane >> 4, l16 = lane & 15;
  floatx4 acc[4];
#pragma unroll
  for (int nt = 0; nt < 4; ++nt) acc[nt] = (floatx4){0.f, 0.f, 0.f, 0.f};
#pragma unroll
  for (int kh = 0; kh < 64; kh += 32) {
    bf16x8 a = *(const bf16x8*)&As[w * 16 + l16][kh + quad * 8];
#pragma unroll
    for (int nt = 0; nt < 4; ++nt) {
      bf16x8 b = *(const bf16x8*)&Bs[nt * 16 + l16][kh + quad * 8];
      acc[nt] = __builtin_amdgcn_mfma_f32_16x16x32_bf16(a, b, acc[nt], 0, 0, 0);
    }
  }
  float sc = fmaxf(acq[0], EPSQ) * fmaxf(ack[0], EPSQ) * 0.125f;  // /sqrt(64)
#pragma unroll
  for (int nt = 0; nt < 4; ++nt)
#pragma unroll
    for (int r = 0; r < 4; ++r) {
      int qr = q0 + w * 16 + quad * 4 + r;
      int c  = c0 + nt * 16 + l16;
      scores[((size_t)bh * 1024 + qr) * 1024 + c] = sc * acc[nt][r];
    }
}

// ---------------- per-row max / sumexp / global min(attn) ----------------
__global__ __launch_bounds__(256) void k_rowstats(
    const float* scores, float* rmax, float* rsum, int* mnbits) {
  __shared__ float red[256];
  int r = blockIdx.x, t = threadIdx.x;
  const float* p = scores + (size_t)r * 1024;
  float x0 = p[t], x1 = p[t + 256], x2 = p[t + 512], x3 = p[t + 768];
  float mx = fmaxf(fmaxf(x0, x1), fmaxf(x2, x3));
  red[t] = mx; __syncthreads();
  for (int o = 128; o > 0; o >>= 1) { if (t < o) red[t] = fmaxf(red[t], red[t + o]); __syncthreads(); }
  float rowmax = red[0]; __syncthreads();
  float se = expf(x0 - rowmax) + expf(x1 - rowmax) + expf(x2 - rowmax) + expf(x3 - rowmax);
  red[t] = se; __syncthreads();
  for (int o = 128; o > 0; o >>= 1) { if (t < o) red[t] += red[t + o]; __syncthreads(); }
  float rowsum = red[0]; __syncthreads();
  float mn4 = fminf(fminf(x0, x1), fminf(x2, x3));
  red[t] = mn4; __syncthreads();
  for (int o = 128; o > 0; o >>= 1) { if (t < o) red[t] = fminf(red[t], red[t + o]); __syncthreads(); }
  if (t == 0) {
    rmax[r] = rowmax; rsum[r] = rowsum;
    float cand = expf(red[0] - rowmax) / rowsum;  // same expr as k_pv staging
    atomicMin(mnbits, __float_as_int(cand));      // positive floats: int order == float order
  }
}

// ------- softmax + uns4 fused into A-staging, PV MFMA, sig8 -> ctxq (view layout) -------
__global__ __launch_bounds__(256) void k_pv(
    const float* scores, const float* rmax, const float* rsum,
    const int* mnbits, const int* colsum, const int8_t* vt,
    const float* acattn, const float* acv, const float* ao,
    int8_t* ctxq) {
  __shared__ __align__(16) __bf16 As[64][AS];
  __shared__ __align__(16) __bf16 Bs[64][AS];
  int bh = blockIdx.y;
  int m0 = blockIdx.x * 64;
  float mn = __int_as_float(*mnbits);
  float a_att = fmaxf(acattn[0], EPSQ);
  float a_v   = fmaxf(acv[0], EPSQ);
  float a_o   = fmaxf(ao[0], EPSQ);
  const float* Sp  = scores + (size_t)bh * 1048576;
  const int8_t* Vt = vt + (size_t)bh * 65536;
  int t = threadIdx.x;
  int lane = t & 63, w = t >> 6, quad = lane >> 4, l16 = lane & 15;
  floatx4 acc[4];
#pragma unroll
  for (int nt = 0; nt < 4; ++nt) acc[nt] = (floatx4){0.f, 0.f, 0.f, 0.f};

  for (int k0 = 0; k0 < 1024; k0 += 64) {
#pragma unroll
    for (int i = 0; i < 16; ++i) {
      int idx = t + i * 256;
      int c = idx & 63, m = idx >> 6;
      int r = bh * 1024 + m0 + m;
      float s = Sp[(size_t)(m0 + m) * 1024 + k0 + c];
      float attn = expf(s - rmax[r]) / rsum[r];
      As[m][c] = (__bf16)clampf(rintf((attn - mn) / a_att), 0.f, 15.f);
      Bs[m][c] = (__bf16)(float)Vt[(size_t)m * 1024 + k0 + c];  // Bs[dd][c]
    }
    __syncthreads();
#pragma unroll
    for (int kh = 0; kh < 64; kh += 32) {
      bf16x8 a = *(const bf16x8*)&As[w * 16 + l16][kh + quad * 8];
#pragma unroll
      for (int nt = 0; nt < 4; ++nt) {
        bf16x8 b = *(const bf16x8*)&Bs[nt * 16 + l16][kh + quad * 8];
        acc[nt] = __builtin_amdgcn_mfma_f32_16x16x32_bf16(a, b, acc[nt], 0, 0, 0);
      }
    }
    __syncthreads();
  }
  float sc  = a_att * a_v;
  float mnv = mn * a_v;
  int b = bh >> 3, h = bh & 7;
#pragma unroll
  for (int nt = 0; nt < 4; ++nt) {
    int dd = nt * 16 + l16;
    float cs = (float)colsum[bh * 64 + dd];
#pragma unroll
    for (int r = 0; r < 4; ++r) {
      int srow = m0 + w * 16 + quad * 4 + r;
      float ctx = sc * acc[nt][r] + mnv * cs;
      float c8 = clampf(rintf(ctx / a_o), -128.f, 127.f);
      // ctx[b,h,s,dd] -> view[b, h*128 + s/8, (s%8)*64 + dd]
      ctxq[(size_t)b * 524288 + (size_t)(h * 128 + (srow >> 3)) * 512 + (srow & 7) * 64 + dd] = (int8_t)c8;
    }
  }
}

// ---------------- output projection MFMA ----------------
__global__ __launch_bounds__(256) void k_outg(
    const int8_t* ctxq, const int8_t* signs_o,
    const float* wabs, const float* ao, float* outb) {
  __shared__ __align__(16) __bf16 As[64][AS];
  __shared__ __align__(16) __bf16 Bs[64][AS];
  int n0 = blockIdx.x * 64, f0 = blockIdx.y * 64;
  int t = threadIdx.x;
  int lane = t & 63, w = t >> 6, quad = lane >> 4, l16 = lane & 15;
  floatx4 acc[4];
#pragma unroll
  for (int nt = 0; nt < 4; ++nt) acc[nt] = (floatx4){0.f, 0.f, 0.f, 0.f};
  for (int k0 = 0; k0 < 512; k0 += 64) {
#pragma unroll
    for (int i = 0; i < 16; ++i) {
      int idx = t + i * 256;
      int kk = idx & 63, m = idx >> 6;
      As[m][kk] = (__bf16)(float)ctxq[(size_t)(n0 + m) * 512 + k0 + kk];
      Bs[m][kk] = (__bf16)(float)signs_o[(size_t)(f0 + m) * 512 + k0 + kk];
    }
    __syncthreads();
#pragma unroll
    for (int kh = 0; kh < 64; kh += 32) {
      bf16x8 a = *(const bf16x8*)&As[w * 16 + l16][kh + quad * 8];
#pragma unroll
      for (int nt = 0; nt < 4; ++nt) {
        bf16x8 b = *(const bf16x8*)&Bs[nt * 16 + l16][kh + quad * 8];
        acc[nt] = __builtin_amdgcn_mfma_f32_16x16x32_bf16(a, b, acc[nt], 0, 0, 0);
      }
    }
    __syncthreads();
  }
  float scale = fmaxf(ao[0], EPSQ) * (wabs[3] * (1.0f / 262144.0f));
#pragma unroll
  for (int nt = 0; nt < 4; ++nt)
#pragma unroll
    for (int r = 0; r < 4; ++r)
      outb[(size_t)(n0 + w * 16 + quad * 4 + r) * 512 + f0 + nt * 16 + l16] = scale * acc[nt][r];
}

// ---------------- layernorm(q + out) -> output 0 ----------------
__global__ __launch_bounds__(256) void k_ln(
    const float* q, const float* outb, const float* g, const float* bb, float* out0) {
  __shared__ float red[256];
  int r = blockIdx.x, t = threadIdx.x;
  const float* qp = q + (size_t)r * 512;
  const float* op = outb + (size_t)r * 512;
  float y0 = qp[t] + op[t];
  float y1 = qp[t + 256] + op[t + 256];
  red[t] = y0 + y1; __syncthreads();
  for (int o = 128; o > 0; o >>= 1) { if (t < o) red[t] += red[t + o]; __syncthreads(); }
  float mu = red[0] * (1.0f / 512.0f); __syncthreads();
  float d0 = y0 - mu, d1 = y1 - mu;
  red[t] = d0 * d0 + d1 * d1; __syncthreads();
  for (int o = 128; o > 0; o >>= 1) { if (t < o) red[t] += red[t + o]; __syncthreads(); }
  float var = red[0] * (1.0f / 512.0f);
  float den = sqrtf(var + 1e-5f);
  out0[(size_t)r * 512 + t]       = d0 / den * g[t] + bb[t];
  out0[(size_t)r * 512 + t + 256] = d1 / den * g[t + 256] + bb[t + 256];
}

extern "C" void kernel_launch(void* const* d_in, const int* in_sizes, int n_in,
                              void* d_out, int out_size, void* d_ws, size_t ws_size,
                              hipStream_t stream) {
  const float* q   = (const float*)d_in[0];
  const float* k   = (const float*)d_in[1];
  const float* v   = (const float*)d_in[2];
  // d_in[3] = mask (int32) — structurally unused by the reference
  const float* Wq  = (const float*)d_in[4];
  const float* Wk  = (const float*)d_in[5];
  const float* Wv  = (const float*)d_in[6];
  const float* Wo  = (const float*)d_in[7];
  const float* bq  = (const float*)d_in[8];
  const float* bk  = (const float*)d_in[9];
  const float* bv  = (const float*)d_in[10];
  const float* lng = (const float*)d_in[11];
  const float* lnb = (const float*)d_in[12];
  const float* aq  = (const float*)d_in[13];
  const float* ak  = (const float*)d_in[14];
  const float* av  = (const float*)d_in[15];
  const float* acq = (const float*)d_in[16];
  const float* ack = (const float*)d_in[17];
  const float* acv = (const float*)d_in[18];
  const float* aca = (const float*)d_in[19];
  const float* ao  = (const float*)d_in[20];

  char* ws = (char*)d_ws;
  float* wsum   = (float*)(ws + O_WSUM);
  float* wabs   = (float*)(ws + O_WABS);
  int*   mnb    = (int*)(ws + O_MN);
  int*   colsum = (int*)(ws + O_COLSUM);
  int8_t* signs = (int8_t*)(ws + O_SIGNS);
  int8_t* kqb   = (int8_t*)(ws + O_KQ);
  int8_t* kkb   = (int8_t*)(ws + O_KK);
  int8_t* kvb   = (int8_t*)(ws + O_KV);
  int8_t* vtb   = (int8_t*)(ws + O_VT);
  float* rmax   = (float*)(ws + O_RMAX);
  float* rsum   = (float*)(ws + O_RSUM);
  int8_t* ctxq  = (int8_t*)(ws + O_CTXQ);
  float* outb   = (float*)(ws + O_OUTB);

  float* out0   = (float*)d_out;
  float* scores = (float*)d_out + OUT0N;

  k_init<<<1, 256, 0, stream>>>(wsum, wabs, mnb, colsum);
  k_wstats<<<256, 256, 0, stream>>>(Wq, Wk, Wv, Wo, wsum, wabs);
  k_sign<<<4096, 256, 0, stream>>>(Wq, Wk, Wv, Wo, wsum, signs);
  k_proj<<<dim3(64, 8, 3), 256, 0, stream>>>(q, k, v, bq, bk, bv, aq, ak, av,
                                             acq, ack, acv, signs, wabs, kqb, kkb, kvb);
  k_vt<<<32, 256, 0, stream>>>(kvb, vtb, colsum);
  k_qk<<<dim3(16, 16, 32), 256, 0, stream>>>(kqb, kkb, acq, ack, scores);
  k_rowstats<<<32768, 256, 0, stream>>>(scores, rmax, rsum, mnb);
  k_pv<<<dim3(16, 32), 256, 0, stream>>>(scores, rmax, rsum, mnb, colsum, vtb,
                                         aca, acv, ao, ctxq);
  k_outg<<<dim3(64, 8), 256, 0, stream>>>(ctxq, signs + 3 * WELEM, wabs, ao, outb);
  k_ln<<<4096, 256, 0, stream>>>(q, outb, lng, lnb, out0);
}

// Round 3
// 438.361 us; speedup vs baseline: 2.9620x; 2.2776x over previous
//
#include <hip/hip_runtime.h>
#include <math.h>
#include <stdint.h>

#define EPSQ 1e-5f
#define WELEM 262144          // 512*512
#define OUT0N 2097152         // 4*1024*512

// ---- workspace byte offsets ----
#define O_WSUM   0                       // float[4]  sum(W)
#define O_WABS   16                      // float[4]  sum|W|
#define O_MN     32                      // float     global min(attn)
#define O_COLSUM 64                      // int[2048] colsum of kv per (bh,dd)
#define O_SIGNS  16384                   // int8[4*262144]
#define O_KQ     (O_SIGNS + 4*WELEM)     // int8[32*1024*64] per-head q levels
#define O_KK     (O_KQ + 2097152)
#define O_KV     (O_KK + 2097152)
#define O_VT     (O_KV + 2097152)        // int8[32][64][1024] V transposed
#define O_RMAX   (O_VT + 2097152)        // float[32768]
#define O_RSUM   (O_RMAX + 131072)       // float[32768]
#define O_CTXQ   (O_RSUM + 131072)       // int8[2097152]  sig8 levels, view layout
#define O_OUTB   (O_CTXQ + 2097152)      // float[2097152] out before LN
#define O_RCAND  O_OUTB                  // float[32768] overlays outb (disjoint lifetime)

#define AS 72  // LDS row stride in bf16 elems: 144 B, 16B-aligned, conflict-benign

typedef __bf16 bf16x8 __attribute__((ext_vector_type(8)));
typedef __bf16 bf16x4 __attribute__((ext_vector_type(4)));
typedef float  floatx4 __attribute__((ext_vector_type(4)));

__device__ __forceinline__ float clampf(float x, float lo, float hi) {
  return fminf(fmaxf(x, lo), hi);
}

// unpack 16 int8 -> 16 bf16 into LDS row at [k16]
__device__ __forceinline__ void unpack16(__bf16* dst, int4 raw) {
  const int8_t* sb = (const int8_t*)&raw;
  __bf16 tmp[16];
#pragma unroll
  for (int j = 0; j < 16; ++j) tmp[j] = (__bf16)(float)sb[j];
  *(bf16x8*)&dst[0] = *(bf16x8*)&tmp[0];
  *(bf16x8*)&dst[8] = *(bf16x8*)&tmp[8];
}

// ---------------- init ----------------
__global__ void k_init(float* wsum, float* wabs, int* colsum) {
  int t = threadIdx.x;
  if (t < 4) { wsum[t] = 0.f; wabs[t] = 0.f; }
  for (int i = t; i < 2048; i += 256) colsum[i] = 0;
}

// ---------------- weight stats ----------------
__global__ void k_wstats(const float* Wq, const float* Wk, const float* Wv, const float* Wo,
                         float* wsum, float* wabs) {
  __shared__ float s1[256], s2[256];
  int w = blockIdx.x >> 6;
  const float* W = (w == 0) ? Wq : (w == 1) ? Wk : (w == 2) ? Wv : Wo;
  int base = (blockIdx.x & 63) * 4096;
  float s = 0.f, sa = 0.f;
  for (int i = threadIdx.x; i < 4096; i += 256) {
    float x = W[base + i];
    s += x; sa += fabsf(x);
  }
  s1[threadIdx.x] = s; s2[threadIdx.x] = sa; __syncthreads();
  for (int o = 128; o > 0; o >>= 1) {
    if (threadIdx.x < o) { s1[threadIdx.x] += s1[threadIdx.x + o]; s2[threadIdx.x] += s2[threadIdx.x + o]; }
    __syncthreads();
  }
  if (threadIdx.x == 0) { atomicAdd(&wsum[w], s1[0]); atomicAdd(&wabs[w], s2[0]); }
}

// ---------------- binarize ----------------
__global__ void k_sign(const float* Wq, const float* Wk, const float* Wv, const float* Wo,
                       const float* wsum, int8_t* signs) {
  int idx = blockIdx.x * 256 + threadIdx.x;
  int w = idx >> 18;
  int pos = idx & (WELEM - 1);
  const float* W = (w == 0) ? Wq : (w == 1) ? Wk : (w == 2) ? Wv : Wo;
  float e = wsum[w] * (1.0f / 262144.0f);
  float x = W[pos];
  signs[idx] = (int8_t)((x > e) - (x < e));
}

// ---------------- projection: MFMA int-exact bf16 GEMM + head quant ----------------
__global__ __launch_bounds__(256) void k_proj(
    const float* q, const float* kin, const float* vin,
    const float* bq, const float* bk, const float* bv,
    const float* aq, const float* ak, const float* av,
    const float* acq, const float* ack, const float* acv,
    const int8_t* signs, const float* wabs,
    int8_t* kqo, int8_t* kko, int8_t* kvo) {
  __shared__ __align__(16) __bf16 As[64][AS];
  __shared__ __align__(16) __bf16 Bs[64][AS];
  int z = blockIdx.z;
  const float* X    = (z == 0) ? q   : (z == 1) ? kin : vin;
  const float* bias = (z == 0) ? bq  : (z == 1) ? bk  : bv;
  const float* aip  = (z == 0) ? aq  : (z == 1) ? ak  : av;
  const float* ahp  = (z == 0) ? acq : (z == 1) ? ack : acv;
  int8_t* outp      = (z == 0) ? kqo : (z == 1) ? kko : kvo;
  float a_in = fmaxf(aip[0], EPSQ);
  float a_hd = fmaxf(ahp[0], EPSQ);
  float m_w  = wabs[z] * (1.0f / 262144.0f);
  const int8_t* S = signs + (size_t)z * WELEM;

  int n0 = blockIdx.x * 64;
  int f0 = blockIdx.y * 64;
  int t = threadIdx.x;
  int lane = t & 63, w = t >> 6, quad = lane >> 4, l16 = lane & 15;
  int c4 = (t & 15) * 4, mb = t >> 4;          // A-staging coords
  int k16 = (t & 3) * 16, mrow = t >> 2;       // B-staging coords
  floatx4 acc[4];
#pragma unroll
  for (int nt = 0; nt < 4; ++nt) acc[nt] = (floatx4){0.f, 0.f, 0.f, 0.f};

  for (int k0 = 0; k0 < 512; k0 += 64) {
#pragma unroll
    for (int j = 0; j < 4; ++j) {             // A: fp32 x4 -> quant levels
      int m = mb + j * 16;
      float4 x = *(const float4*)&X[(size_t)(n0 + m) * 512 + k0 + c4];
      bf16x4 av = { (__bf16)clampf(rintf(x.x / a_in), -8.f, 7.f),
                    (__bf16)clampf(rintf(x.y / a_in), -8.f, 7.f),
                    (__bf16)clampf(rintf(x.z / a_in), -8.f, 7.f),
                    (__bf16)clampf(rintf(x.w / a_in), -8.f, 7.f) };
      *(bf16x4*)&As[m][c4] = av;
    }
    {                                          // B: 16 sign bytes per thread
      int4 raw = *(const int4*)&S[(size_t)(f0 + mrow) * 512 + k0 + k16];
      unpack16(&Bs[mrow][k16], raw);
    }
    __syncthreads();
#pragma unroll
    for (int kh = 0; kh < 64; kh += 32) {
      bf16x8 a = *(const bf16x8*)&As[w * 16 + l16][kh + quad * 8];
#pragma unroll
      for (int nt = 0; nt < 4; ++nt) {
        bf16x8 b = *(const bf16x8*)&Bs[nt * 16 + l16][kh + quad * 8];
        acc[nt] = __builtin_amdgcn_mfma_f32_16x16x32_bf16(a, b, acc[nt], 0, 0, 0);
      }
    }
    __syncthreads();
  }
  float s_am = a_in * m_w;
#pragma unroll
  for (int nt = 0; nt < 4; ++nt) {
    int f = f0 + nt * 16 + l16;
    int h = f >> 6, dd = f & 63;
    float bia = bias[f];
#pragma unroll
    for (int r = 0; r < 4; ++r) {
      int n = n0 + w * 16 + quad * 4 + r;
      int b = n >> 10, srow = n & 1023;
      float P = s_am * acc[nt][r] + bia;
      float hq = clampf(rintf(P / a_hd), -8.f, 7.f);
      outp[(size_t)((b * 8 + h) * 1024 + srow) * 64 + dd] = (int8_t)hq;
    }
  }
}

// ---------------- V transpose + column sums ----------------
__global__ __launch_bounds__(256) void k_vt(const int8_t* kv, int8_t* vt, int* colsum) {
  __shared__ int red[256];
  int bh = blockIdx.x;
  int t = threadIdx.x;
  int dd = t & 63, part = t >> 6;
  const int8_t* p = kv + (size_t)bh * 65536;
  int8_t* o = vt + (size_t)bh * 65536;
  int acc = 0;
  for (int s = part * 256; s < part * 256 + 256; ++s) {
    int8_t val = p[s * 64 + dd];
    o[dd * 1024 + s] = val;
    acc += val;
  }
  red[t] = acc; __syncthreads();
  if (part == 0) colsum[bh * 64 + dd] = red[dd] + red[64 + dd] + red[128 + dd] + red[192 + dd];
}

// ---------------- QK^T MFMA -> scores (output 1) ----------------
__global__ __launch_bounds__(256) void k_qk(
    const int8_t* kq, const int8_t* kkv,
    const float* acq, const float* ack, float* scores) {
  __shared__ __align__(16) __bf16 As[64][AS];
  __shared__ __align__(16) __bf16 Bs[64][AS];
  int bh = blockIdx.z;
  int q0 = blockIdx.x * 64, c0 = blockIdx.y * 64;
  const int8_t* A  = kq  + (size_t)bh * 65536;
  const int8_t* Bp = kkv + (size_t)bh * 65536;
  int t = threadIdx.x;
  int k16 = (t & 3) * 16, mrow = t >> 2;
  {
    int4 ra = *(const int4*)&A[(q0 + mrow) * 64 + k16];
    int4 rb = *(const int4*)&Bp[(c0 + mrow) * 64 + k16];
    unpack16(&As[mrow][k16], ra);
    unpack16(&Bs[mrow][k16], rb);
  }
  __syncthreads();
  int lane = t & 63, w = t >> 6, quad = lane >> 4, l16 = lane & 15;
  floatx4 acc[4];
#pragma unroll
  for (int nt = 0; nt < 4; ++nt) acc[nt] = (floatx4){0.f, 0.f, 0.f, 0.f};
#pragma unroll
  for (int kh = 0; kh < 64; kh += 32) {
    bf16x8 a = *(const bf16x8*)&As[w * 16 + l16][kh + quad * 8];
#pragma unroll
    for (int nt = 0; nt < 4; ++nt) {
      bf16x8 b = *(const bf16x8*)&Bs[nt * 16 + l16][kh + quad * 8];
      acc[nt] = __builtin_amdgcn_mfma_f32_16x16x32_bf16(a, b, acc[nt], 0, 0, 0);
    }
  }
  float sc = fmaxf(acq[0], EPSQ) * fmaxf(ack[0], EPSQ) * 0.125f;  // /sqrt(64)
#pragma unroll
  for (int nt = 0; nt < 4; ++nt)
#pragma unroll
    for (int r = 0; r < 4; ++r) {
      int qr = q0 + w * 16 + quad * 4 + r;
      int c  = c0 + nt * 16 + l16;
      scores[((size_t)bh * 1024 + qr) * 1024 + c] = sc * acc[nt][r];
    }
}

// ------- per-row stats: one wave per row, shuffle reductions, NO atomics -------
__global__ __launch_bounds__(256) void k_rowstats(
    const float* scores, float* rmax, float* rsum, float* rcand) {
  int wv = threadIdx.x >> 6, lane = threadIdx.x & 63;
  int r = blockIdx.x * 4 + wv;
  const float* p = scores + (size_t)r * 1024;
  float4 x[4];
#pragma unroll
  for (int j = 0; j < 4; ++j) x[j] = *(const float4*)&p[lane * 4 + j * 256];
  float mx = -INFINITY, mn = INFINITY;
#pragma unroll
  for (int j = 0; j < 4; ++j) {
    mx = fmaxf(mx, fmaxf(fmaxf(x[j].x, x[j].y), fmaxf(x[j].z, x[j].w)));
    mn = fminf(mn, fminf(fminf(x[j].x, x[j].y), fminf(x[j].z, x[j].w)));
  }
#pragma unroll
  for (int o = 32; o > 0; o >>= 1) {
    mx = fmaxf(mx, __shfl_xor(mx, o));
    mn = fminf(mn, __shfl_xor(mn, o));
  }
  float se = 0.f;
#pragma unroll
  for (int j = 0; j < 4; ++j)
    se += expf(x[j].x - mx) + expf(x[j].y - mx) + expf(x[j].z - mx) + expf(x[j].w - mx);
#pragma unroll
  for (int o = 32; o > 0; o >>= 1) se += __shfl_xor(se, o);
  if (lane == 0) {
    rmax[r] = mx; rsum[r] = se;
    rcand[r] = expf(mn - mx) / se;  // same expr as k_pv staging
  }
}

// ---------------- global min of rcand (single block) ----------------
__global__ __launch_bounds__(1024) void k_minred(const float* rcand, float* mnf) {
  __shared__ float red[1024];
  float mn = INFINITY;
  for (int i = threadIdx.x; i < 32768; i += 1024) mn = fminf(mn, rcand[i]);
  red[threadIdx.x] = mn; __syncthreads();
  for (int o = 512; o > 0; o >>= 1) {
    if (threadIdx.x < o) red[threadIdx.x] = fminf(red[threadIdx.x], red[threadIdx.x + o]);
    __syncthreads();
  }
  if (threadIdx.x == 0) mnf[0] = red[0];
}

// ------- softmax + uns4 fused into A-staging, PV MFMA, sig8 -> ctxq (view layout) -------
__global__ __launch_bounds__(256) void k_pv(
    const float* scores, const float* rmax, const float* rsum,
    const float* mnf, const int* colsum, const int8_t* vt,
    const float* acattn, const float* acv, const float* ao,
    int8_t* ctxq) {
  __shared__ __align__(16) __bf16 As[64][AS];
  __shared__ __align__(16) __bf16 Bs[64][AS];
  int bh = blockIdx.y;
  int m0 = blockIdx.x * 64;
  float mn = mnf[0];
  float a_att = fmaxf(acattn[0], EPSQ);
  float a_v   = fmaxf(acv[0], EPSQ);
  float a_o   = fmaxf(ao[0], EPSQ);
  const float* Sp  = scores + (size_t)bh * 1048576;
  const int8_t* Vt = vt + (size_t)bh * 65536;
  int t = threadIdx.x;
  int lane = t & 63, w = t >> 6, quad = lane >> 4, l16 = lane & 15;
  int c4 = (t & 15) * 4, mb = t >> 4;
  int k16 = (t & 3) * 16, mrow = t >> 2;
  // hoist per-row softmax stats (4 rows per thread, fixed across K)
  float rm[4], rs[4];
#pragma unroll
  for (int j = 0; j < 4; ++j) {
    int r = bh * 1024 + m0 + mb + j * 16;
    rm[j] = rmax[r]; rs[j] = rsum[r];
  }
  floatx4 acc[4];
#pragma unroll
  for (int nt = 0; nt < 4; ++nt) acc[nt] = (floatx4){0.f, 0.f, 0.f, 0.f};

  for (int k0 = 0; k0 < 1024; k0 += 64) {
#pragma unroll
    for (int j = 0; j < 4; ++j) {   // A: scores -> attn -> uns4 levels
      int m = mb + j * 16;
      float4 s4 = *(const float4*)&Sp[(size_t)(m0 + m) * 1024 + k0 + c4];
      float inv = 1.0f / rs[j];
      bf16x4 av = {
        (__bf16)clampf(rintf((expf(s4.x - rm[j]) * inv - mn) / a_att), 0.f, 15.f),
        (__bf16)clampf(rintf((expf(s4.y - rm[j]) * inv - mn) / a_att), 0.f, 15.f),
        (__bf16)clampf(rintf((expf(s4.z - rm[j]) * inv - mn) / a_att), 0.f, 15.f),
        (__bf16)clampf(rintf((expf(s4.w - rm[j]) * inv - mn) / a_att), 0.f, 15.f) };
      *(bf16x4*)&As[m][c4] = av;
    }
    {                                // B: Vt levels
      int4 raw = *(const int4*)&Vt[(size_t)mrow * 1024 + k0 + k16];
      unpack16(&Bs[mrow][k16], raw);
    }
    __syncthreads();
#pragma unroll
    for (int kh = 0; kh < 64; kh += 32) {
      bf16x8 a = *(const bf16x8*)&As[w * 16 + l16][kh + quad * 8];
#pragma unroll
      for (int nt = 0; nt < 4; ++nt) {
        bf16x8 b = *(const bf16x8*)&Bs[nt * 16 + l16][kh + quad * 8];
        acc[nt] = __builtin_amdgcn_mfma_f32_16x16x32_bf16(a, b, acc[nt], 0, 0, 0);
      }
    }
    __syncthreads();
  }
  float sc  = a_att * a_v;
  float mnv = mn * a_v;
  int b = bh >> 3, h = bh & 7;
#pragma unroll
  for (int nt = 0; nt < 4; ++nt) {
    int dd = nt * 16 + l16;
    float cs = (float)colsum[bh * 64 + dd];
#pragma unroll
    for (int r = 0; r < 4; ++r) {
      int srow = m0 + w * 16 + quad * 4 + r;
      float ctx = sc * acc[nt][r] + mnv * cs;
      float c8 = clampf(rintf(ctx / a_o), -128.f, 127.f);
      // ctx[b,h,s,dd] -> view[b, h*128 + s/8, (s%8)*64 + dd]
      ctxq[(size_t)b * 524288 + (size_t)(h * 128 + (srow >> 3)) * 512 + (srow & 7) * 64 + dd] = (int8_t)c8;
    }
  }
}

// ---------------- output projection MFMA ----------------
__global__ __launch_bounds__(256) void k_outg(
    const int8_t* ctxq, const int8_t* signs_o,
    const float* wabs, const float* ao, float* outb) {
  __shared__ __align__(16) __bf16 As[64][AS];
  __shared__ __align__(16) __bf16 Bs[64][AS];
  int n0 = blockIdx.x * 64, f0 = blockIdx.y * 64;
  int t = threadIdx.x;
  int lane = t & 63, w = t >> 6, quad = lane >> 4, l16 = lane & 15;
  int k16 = (t & 3) * 16, mrow = t >> 2;
  floatx4 acc[4];
#pragma unroll
  for (int nt = 0; nt < 4; ++nt) acc[nt] = (floatx4){0.f, 0.f, 0.f, 0.f};
  for (int k0 = 0; k0 < 512; k0 += 64) {
    {
      int4 ra = *(const int4*)&ctxq[(size_t)(n0 + mrow) * 512 + k0 + k16];
      int4 rb = *(const int4*)&signs_o[(size_t)(f0 + mrow) * 512 + k0 + k16];
      unpack16(&As[mrow][k16], ra);
      unpack16(&Bs[mrow][k16], rb);
    }
    __syncthreads();
#pragma unroll
    for (int kh = 0; kh < 64; kh += 32) {
      bf16x8 a = *(const bf16x8*)&As[w * 16 + l16][kh + quad * 8];
#pragma unroll
      for (int nt = 0; nt < 4; ++nt) {
        bf16x8 b = *(const bf16x8*)&Bs[nt * 16 + l16][kh + quad * 8];
        acc[nt] = __builtin_amdgcn_mfma_f32_16x16x32_bf16(a, b, acc[nt], 0, 0, 0);
      }
    }
    __syncthreads();
  }
  float scale = fmaxf(ao[0], EPSQ) * (wabs[3] * (1.0f / 262144.0f));
#pragma unroll
  for (int nt = 0; nt < 4; ++nt)
#pragma unroll
    for (int r = 0; r < 4; ++r)
      outb[(size_t)(n0 + w * 16 + quad * 4 + r) * 512 + f0 + nt * 16 + l16] = scale * acc[nt][r];
}

// ---------------- layernorm(q + out) -> output 0 ----------------
__global__ __launch_bounds__(256) void k_ln(
    const float* q, const float* outb, const float* g, const float* bb, float* out0) {
  __shared__ float red[256];
  int r = blockIdx.x, t = threadIdx.x;
  const float* qp = q + (size_t)r * 512;
  const float* op = outb + (size_t)r * 512;
  float y0 = qp[t] + op[t];
  float y1 = qp[t + 256] + op[t + 256];
  red[t] = y0 + y1; __syncthreads();
  for (int o = 128; o > 0; o >>= 1) { if (t < o) red[t] += red[t + o]; __syncthreads(); }
  float mu = red[0] * (1.0f / 512.0f); __syncthreads();
  float d0 = y0 - mu, d1 = y1 - mu;
  red[t] = d0 * d0 + d1 * d1; __syncthreads();
  for (int o = 128; o > 0; o >>= 1) { if (t < o) red[t] += red[t + o]; __syncthreads(); }
  float var = red[0] * (1.0f / 512.0f);
  float den = sqrtf(var + 1e-5f);
  out0[(size_t)r * 512 + t]       = d0 / den * g[t] + bb[t];
  out0[(size_t)r * 512 + t + 256] = d1 / den * g[t + 256] + bb[t + 256];
}

extern "C" void kernel_launch(void* const* d_in, const int* in_sizes, int n_in,
                              void* d_out, int out_size, void* d_ws, size_t ws_size,
                              hipStream_t stream) {
  const float* q   = (const float*)d_in[0];
  const float* k   = (const float*)d_in[1];
  const float* v   = (const float*)d_in[2];
  // d_in[3] = mask (int32) — structurally unused by the reference
  const float* Wq  = (const float*)d_in[4];
  const float* Wk  = (const float*)d_in[5];
  const float* Wv  = (const float*)d_in[6];
  const float* Wo  = (const float*)d_in[7];
  const float* bq  = (const float*)d_in[8];
  const float* bk  = (const float*)d_in[9];
  const float* bv  = (const float*)d_in[10];
  const float* lng = (const float*)d_in[11];
  const float* lnb = (const float*)d_in[12];
  const float* aq  = (const float*)d_in[13];
  const float* ak  = (const float*)d_in[14];
  const float* av  = (const float*)d_in[15];
  const float* acq = (const float*)d_in[16];
  const float* ack = (const float*)d_in[17];
  const float* acv = (const float*)d_in[18];
  const float* aca = (const float*)d_in[19];
  const float* ao  = (const float*)d_in[20];

  char* ws = (char*)d_ws;
  float* wsum   = (float*)(ws + O_WSUM);
  float* wabs   = (float*)(ws + O_WABS);
  float* mnf    = (float*)(ws + O_MN);
  int*   colsum = (int*)(ws + O_COLSUM);
  int8_t* signs = (int8_t*)(ws + O_SIGNS);
  int8_t* kqb   = (int8_t*)(ws + O_KQ);
  int8_t* kkb   = (int8_t*)(ws + O_KK);
  int8_t* kvb   = (int8_t*)(ws + O_KV);
  int8_t* vtb   = (int8_t*)(ws + O_VT);
  float* rmax   = (float*)(ws + O_RMAX);
  float* rsum   = (float*)(ws + O_RSUM);
  float* rcand  = (float*)(ws + O_RCAND);
  int8_t* ctxq  = (int8_t*)(ws + O_CTXQ);
  float* outb   = (float*)(ws + O_OUTB);

  float* out0   = (float*)d_out;
  float* scores = (float*)d_out + OUT0N;

  k_init<<<1, 256, 0, stream>>>(wsum, wabs, colsum);
  k_wstats<<<256, 256, 0, stream>>>(Wq, Wk, Wv, Wo, wsum, wabs);
  k_sign<<<4096, 256, 0, stream>>>(Wq, Wk, Wv, Wo, wsum, signs);
  k_proj<<<dim3(64, 8, 3), 256, 0, stream>>>(q, k, v, bq, bk, bv, aq, ak, av,
                                             acq, ack, acv, signs, wabs, kqb, kkb, kvb);
  k_vt<<<32, 256, 0, stream>>>(kvb, vtb, colsum);
  k_qk<<<dim3(16, 16, 32), 256, 0, stream>>>(kqb, kkb, acq, ack, scores);
  k_rowstats<<<8192, 256, 0, stream>>>(scores, rmax, rsum, rcand);
  k_minred<<<1, 1024, 0, stream>>>(rcand, mnf);
  k_pv<<<dim3(16, 32), 256, 0, stream>>>(scores, rmax, rsum, mnf, colsum, vtb,
                                         aca, acv, ao, ctxq);
  k_outg<<<dim3(64, 8), 256, 0, stream>>>(ctxq, signs + 3 * WELEM, wabs, ao, outb);
  k_ln<<<4096, 256, 0, stream>>>(q, outb, lng, lnb, out0);
}

// Round 4
// 416.985 us; speedup vs baseline: 3.1139x; 1.0513x over previous
//
#include <hip/hip_runtime.h>
#include <math.h>
#include <stdint.h>

#define EPSQ 1e-5f
#define WELEM 262144          // 512*512
#define OUT0N 2097152         // 4*1024*512

// ---- workspace byte offsets ----
#define O_WSUM   0                       // float[4]  sum(W)
#define O_WABS   16                      // float[4]  sum|W|
#define O_MN     32                      // float     global min(attn)
#define O_COLSUM 64                      // int[2048] colsum of kv per (bh,dd)
#define O_SIGNS  16384                   // int8[4*262144]
#define O_KQ     (O_SIGNS + 4*WELEM)     // int8[32*1024*64] per-head q levels
#define O_KK     (O_KQ + 2097152)
#define O_KV     (O_KK + 2097152)
#define O_VT     (O_KV + 2097152)        // int8[32][64][1024] V transposed
#define O_RMAX   (O_VT + 2097152)        // float[32768]
#define O_RSUM   (O_RMAX + 131072)       // float[32768]
#define O_CTXQ   (O_RSUM + 131072)       // int8[2097152]  sig8 levels, view layout
#define O_OUTB   (O_CTXQ + 2097152)      // float[2097152] out before LN
#define O_RCAND  O_OUTB                  // float[32768] overlays outb (disjoint lifetime)

#define AS 72  // LDS row stride in bf16 elems: 144 B, 16B-aligned, conflict-benign

typedef __bf16 bf16x8 __attribute__((ext_vector_type(8)));
typedef __bf16 bf16x4 __attribute__((ext_vector_type(4)));
typedef float  floatx4 __attribute__((ext_vector_type(4)));

__device__ __forceinline__ float clampf(float x, float lo, float hi) {
  return fminf(fmaxf(x, lo), hi);
}

// unpack 16 int8 -> 16 bf16 into LDS row at [k16]
__device__ __forceinline__ void unpack16(__bf16* dst, int4 raw) {
  const int8_t* sb = (const int8_t*)&raw;
  __bf16 tmp[16];
#pragma unroll
  for (int j = 0; j < 16; ++j) tmp[j] = (__bf16)(float)sb[j];
  *(bf16x8*)&dst[0] = *(bf16x8*)&tmp[0];
  *(bf16x8*)&dst[8] = *(bf16x8*)&tmp[8];
}

// ---------------- init ----------------
__global__ void k_init(float* wsum, float* wabs) {
  int t = threadIdx.x;
  if (t < 4) { wsum[t] = 0.f; wabs[t] = 0.f; }
}

// ---------------- weight stats ----------------
__global__ void k_wstats(const float* Wq, const float* Wk, const float* Wv, const float* Wo,
                         float* wsum, float* wabs) {
  __shared__ float s1[256], s2[256];
  int w = blockIdx.x >> 6;
  const float* W = (w == 0) ? Wq : (w == 1) ? Wk : (w == 2) ? Wv : Wo;
  int base = (blockIdx.x & 63) * 4096;
  float s = 0.f, sa = 0.f;
  for (int i = threadIdx.x; i < 4096; i += 256) {
    float x = W[base + i];
    s += x; sa += fabsf(x);
  }
  s1[threadIdx.x] = s; s2[threadIdx.x] = sa; __syncthreads();
  for (int o = 128; o > 0; o >>= 1) {
    if (threadIdx.x < o) { s1[threadIdx.x] += s1[threadIdx.x + o]; s2[threadIdx.x] += s2[threadIdx.x + o]; }
    __syncthreads();
  }
  if (threadIdx.x == 0) { atomicAdd(&wsum[w], s1[0]); atomicAdd(&wabs[w], s2[0]); }
}

// ---------------- binarize ----------------
__global__ void k_sign(const float* Wq, const float* Wk, const float* Wv, const float* Wo,
                       const float* wsum, int8_t* signs) {
  int idx = blockIdx.x * 256 + threadIdx.x;
  int w = idx >> 18;
  int pos = idx & (WELEM - 1);
  const float* W = (w == 0) ? Wq : (w == 1) ? Wk : (w == 2) ? Wv : Wo;
  float e = wsum[w] * (1.0f / 262144.0f);
  float x = W[pos];
  signs[idx] = (int8_t)((x > e) - (x < e));
}

// ---------------- projection: MFMA int-exact bf16 GEMM + head quant ----------------
__global__ __launch_bounds__(256) void k_proj(
    const float* q, const float* kin, const float* vin,
    const float* bq, const float* bk, const float* bv,
    const float* aq, const float* ak, const float* av,
    const float* acq, const float* ack, const float* acv,
    const int8_t* signs, const float* wabs,
    int8_t* kqo, int8_t* kko, int8_t* kvo) {
  __shared__ __align__(16) __bf16 As[64][AS];
  __shared__ __align__(16) __bf16 Bs[64][AS];
  int z = blockIdx.z;
  const float* X    = (z == 0) ? q   : (z == 1) ? kin : vin;
  const float* bias = (z == 0) ? bq  : (z == 1) ? bk  : bv;
  const float* aip  = (z == 0) ? aq  : (z == 1) ? ak  : av;
  const float* ahp  = (z == 0) ? acq : (z == 1) ? ack : acv;
  int8_t* outp      = (z == 0) ? kqo : (z == 1) ? kko : kvo;
  float a_in = fmaxf(aip[0], EPSQ);
  float a_hd = fmaxf(ahp[0], EPSQ);
  float m_w  = wabs[z] * (1.0f / 262144.0f);
  const int8_t* S = signs + (size_t)z * WELEM;

  int n0 = blockIdx.x * 64;
  int f0 = blockIdx.y * 64;
  int t = threadIdx.x;
  int lane = t & 63, w = t >> 6, quad = lane >> 4, l16 = lane & 15;
  int c4 = (t & 15) * 4, mb = t >> 4;          // A-staging coords
  int k16 = (t & 3) * 16, mrow = t >> 2;       // B-staging coords
  floatx4 acc[4];
#pragma unroll
  for (int nt = 0; nt < 4; ++nt) acc[nt] = (floatx4){0.f, 0.f, 0.f, 0.f};

  for (int k0 = 0; k0 < 512; k0 += 64) {
#pragma unroll
    for (int j = 0; j < 4; ++j) {             // A: fp32 x4 -> quant levels
      int m = mb + j * 16;
      float4 x = *(const float4*)&X[(size_t)(n0 + m) * 512 + k0 + c4];
      bf16x4 av = { (__bf16)clampf(rintf(x.x / a_in), -8.f, 7.f),
                    (__bf16)clampf(rintf(x.y / a_in), -8.f, 7.f),
                    (__bf16)clampf(rintf(x.z / a_in), -8.f, 7.f),
                    (__bf16)clampf(rintf(x.w / a_in), -8.f, 7.f) };
      *(bf16x4*)&As[m][c4] = av;
    }
    {                                          // B: 16 sign bytes per thread
      int4 raw = *(const int4*)&S[(size_t)(f0 + mrow) * 512 + k0 + k16];
      unpack16(&Bs[mrow][k16], raw);
    }
    __syncthreads();
#pragma unroll
    for (int kh = 0; kh < 64; kh += 32) {
      bf16x8 a = *(const bf16x8*)&As[w * 16 + l16][kh + quad * 8];
#pragma unroll
      for (int nt = 0; nt < 4; ++nt) {
        bf16x8 b = *(const bf16x8*)&Bs[nt * 16 + l16][kh + quad * 8];
        acc[nt] = __builtin_amdgcn_mfma_f32_16x16x32_bf16(a, b, acc[nt], 0, 0, 0);
      }
    }
    __syncthreads();
  }
  float s_am = a_in * m_w;
#pragma unroll
  for (int nt = 0; nt < 4; ++nt) {
    int f = f0 + nt * 16 + l16;
    int h = f >> 6, dd = f & 63;
    float bia = bias[f];
#pragma unroll
    for (int r = 0; r < 4; ++r) {
      int n = n0 + w * 16 + quad * 4 + r;
      int b = n >> 10, srow = n & 1023;
      float P = s_am * acc[nt][r] + bia;
      float hq = clampf(rintf(P / a_hd), -8.f, 7.f);
      outp[(size_t)((b * 8 + h) * 1024 + srow) * 64 + dd] = (int8_t)hq;
    }
  }
}

// ---------------- V transpose + column sums ----------------
__global__ __launch_bounds__(256) void k_vt(const int8_t* kv, int8_t* vt, int* colsum) {
  __shared__ int red[256];
  int bh = blockIdx.x;
  int t = threadIdx.x;
  int dd = t & 63, part = t >> 6;
  const int8_t* p = kv + (size_t)bh * 65536;
  int8_t* o = vt + (size_t)bh * 65536;
  int acc = 0;
  for (int s = part * 256; s < part * 256 + 256; ++s) {
    int8_t val = p[s * 64 + dd];
    o[dd * 1024 + s] = val;
    acc += val;
  }
  red[t] = acc; __syncthreads();
  if (part == 0) colsum[bh * 64 + dd] = red[dd] + red[64 + dd] + red[128 + dd] + red[192 + dd];
}

// ------- fused QK^T + online row stats: one block = 64 rows x all 1024 cols -------
__global__ __launch_bounds__(256) void k_qks(
    const int8_t* kq, const int8_t* kkv,
    const float* acq, const float* ack,
    float* scores, float* rmax, float* rsum, float* rcand) {
  __shared__ __align__(16) __bf16 As[64][AS];
  __shared__ __align__(16) __bf16 Bs[64][AS];
  int bh = blockIdx.y;
  int q0 = blockIdx.x * 64;
  const int8_t* A  = kq  + (size_t)bh * 65536;
  const int8_t* Bp = kkv + (size_t)bh * 65536;
  float* Sp = scores + ((size_t)bh * 1024 + q0) * 1024;
  int t = threadIdx.x;
  int lane = t & 63, w = t >> 6, quad = lane >> 4, l16 = lane & 15;
  int k16 = (t & 3) * 16, mrow = t >> 2;
  float sc = fmaxf(acq[0], EPSQ) * fmaxf(ack[0], EPSQ) * 0.125f;  // /sqrt(64)

  // stage A (64 rows x 64 d) once
  {
    int4 ra = *(const int4*)&A[(q0 + mrow) * 64 + k16];
    unpack16(&As[mrow][k16], ra);
  }
  // online stats per lane: rows quad*4+rr of wave-strip, cols {ct,nt,l16}
  float m_run[4], l_run[4], mn_run[4];
#pragma unroll
  for (int rr = 0; rr < 4; ++rr) { m_run[rr] = -INFINITY; l_run[rr] = 0.f; mn_run[rr] = INFINITY; }

  for (int ct = 0; ct < 16; ++ct) {
    __syncthreads();  // covers A-stage (ct=0) and prior-tile B reads (ct>0)
    {
      int4 rb = *(const int4*)&Bp[(ct * 64 + mrow) * 64 + k16];
      unpack16(&Bs[mrow][k16], rb);
    }
    __syncthreads();
    floatx4 acc[4];
#pragma unroll
    for (int nt = 0; nt < 4; ++nt) acc[nt] = (floatx4){0.f, 0.f, 0.f, 0.f};
#pragma unroll
    for (int kh = 0; kh < 64; kh += 32) {
      bf16x8 a = *(const bf16x8*)&As[w * 16 + l16][kh + quad * 8];
#pragma unroll
      for (int nt = 0; nt < 4; ++nt) {
        bf16x8 b = *(const bf16x8*)&Bs[nt * 16 + l16][kh + quad * 8];
        acc[nt] = __builtin_amdgcn_mfma_f32_16x16x32_bf16(a, b, acc[nt], 0, 0, 0);
      }
    }
    // scale, store, update online stats
#pragma unroll
    for (int rr = 0; rr < 4; ++rr) {
      int row = w * 16 + quad * 4 + rr;
      float v[4];
#pragma unroll
      for (int nt = 0; nt < 4; ++nt) {
        v[nt] = sc * acc[nt][rr];
        Sp[(size_t)row * 1024 + ct * 64 + nt * 16 + l16] = v[nt];
      }
      float tmax = fmaxf(fmaxf(v[0], v[1]), fmaxf(v[2], v[3]));
      float tmin = fminf(fminf(v[0], v[1]), fminf(v[2], v[3]));
      mn_run[rr] = fminf(mn_run[rr], tmin);
      float mnew = fmaxf(m_run[rr], tmax);
      float s = 0.f;
#pragma unroll
      for (int nt = 0; nt < 4; ++nt) s += expf(v[nt] - mnew);
      l_run[rr] = l_run[rr] * expf(m_run[rr] - mnew) + s;
      m_run[rr] = mnew;
    }
  }
  // combine 16 K-lanes (l16) per row: flash-style (m,l) merge + min
#pragma unroll
  for (int o = 1; o < 16; o <<= 1) {
#pragma unroll
    for (int rr = 0; rr < 4; ++rr) {
      float mo = __shfl_xor(m_run[rr], o);
      float lo = __shfl_xor(l_run[rr], o);
      float mnew = fmaxf(m_run[rr], mo);
      l_run[rr] = l_run[rr] * expf(m_run[rr] - mnew) + lo * expf(mo - mnew);
      m_run[rr] = mnew;
      mn_run[rr] = fminf(mn_run[rr], __shfl_xor(mn_run[rr], o));
    }
  }
  if (l16 == 0) {
#pragma unroll
    for (int rr = 0; rr < 4; ++rr) {
      int r = bh * 1024 + q0 + w * 16 + quad * 4 + rr;
      rmax[r] = m_run[rr];
      rsum[r] = l_run[rr];
      // same arithmetic as k_pv staging: expf(s-rm)*(1/rs)
      rcand[r] = expf(mn_run[rr] - m_run[rr]) * (1.0f / l_run[rr]);
    }
  }
}

// ---------------- global min of rcand (single block) ----------------
__global__ __launch_bounds__(1024) void k_minred(const float* rcand, float* mnf) {
  __shared__ float red[1024];
  float mn = INFINITY;
  for (int i = threadIdx.x; i < 32768; i += 1024) mn = fminf(mn, rcand[i]);
  red[threadIdx.x] = mn; __syncthreads();
  for (int o = 512; o > 0; o >>= 1) {
    if (threadIdx.x < o) red[threadIdx.x] = fminf(red[threadIdx.x], red[threadIdx.x + o]);
    __syncthreads();
  }
  if (threadIdx.x == 0) mnf[0] = red[0];
}

// ------- softmax + uns4 fused A-staging, PV MFMA, sig8 -> ctxq (view layout) -------
// M=32 tile, 1024 blocks (4/CU, 16 waves/CU); wave = (mt, nt-pair), 2 acc tiles each
__global__ __launch_bounds__(256) void k_pv(
    const float* scores, const float* rmax, const float* rsum,
    const float* mnf, const int* colsum, const int8_t* vt,
    const float* acattn, const float* acv, const float* ao,
    int8_t* ctxq) {
  __shared__ __align__(16) __bf16 As[32][AS];
  __shared__ __align__(16) __bf16 Bs[64][AS];
  int bh = blockIdx.y;
  int m0 = blockIdx.x * 32;
  float mn = mnf[0];
  float a_att = fmaxf(acattn[0], EPSQ);
  float a_v   = fmaxf(acv[0], EPSQ);
  float a_o   = fmaxf(ao[0], EPSQ);
  const float* Sp  = scores + (size_t)bh * 1048576;
  const int8_t* Vt = vt + (size_t)bh * 65536;
  int t = threadIdx.x;
  int lane = t & 63, w = t >> 6, quad = lane >> 4, l16 = lane & 15;
  int mt = w & 1, np = w >> 1;                 // wave's M-tile / N-pair
  int c4 = (t & 15) * 4, mb = t >> 4;          // A-staging (2 rows/thread)
  int k16 = (t & 3) * 16, mrow = t >> 2;       // B-staging
  float rm[2], rs[2];
#pragma unroll
  for (int j = 0; j < 2; ++j) {
    int r = bh * 1024 + m0 + mb + j * 16;
    rm[j] = rmax[r]; rs[j] = rsum[r];
  }
  floatx4 acc[2];
  acc[0] = (floatx4){0.f, 0.f, 0.f, 0.f};
  acc[1] = (floatx4){0.f, 0.f, 0.f, 0.f};

  for (int k0 = 0; k0 < 1024; k0 += 64) {
#pragma unroll
    for (int j = 0; j < 2; ++j) {   // A: scores -> attn -> uns4 levels
      int m = mb + j * 16;
      float4 s4 = *(const float4*)&Sp[(size_t)(m0 + m) * 1024 + k0 + c4];
      float inv = 1.0f / rs[j];
      bf16x4 av = {
        (__bf16)clampf(rintf((expf(s4.x - rm[j]) * inv - mn) / a_att), 0.f, 15.f),
        (__bf16)clampf(rintf((expf(s4.y - rm[j]) * inv - mn) / a_att), 0.f, 15.f),
        (__bf16)clampf(rintf((expf(s4.z - rm[j]) * inv - mn) / a_att), 0.f, 15.f),
        (__bf16)clampf(rintf((expf(s4.w - rm[j]) * inv - mn) / a_att), 0.f, 15.f) };
      *(bf16x4*)&As[m][c4] = av;
    }
    {                                // B: Vt levels
      int4 raw = *(const int4*)&Vt[(size_t)mrow * 1024 + k0 + k16];
      unpack16(&Bs[mrow][k16], raw);
    }
    __syncthreads();
#pragma unroll
    for (int kh = 0; kh < 64; kh += 32) {
      bf16x8 a = *(const bf16x8*)&As[mt * 16 + l16][kh + quad * 8];
#pragma unroll
      for (int j = 0; j < 2; ++j) {
        bf16x8 b = *(const bf16x8*)&Bs[(np * 2 + j) * 16 + l16][kh + quad * 8];
        acc[j] = __builtin_amdgcn_mfma_f32_16x16x32_bf16(a, b, acc[j], 0, 0, 0);
      }
    }
    __syncthreads();
  }
  float sc  = a_att * a_v;
  float mnv = mn * a_v;
  int b = bh >> 3, h = bh & 7;
#pragma unroll
  for (int j = 0; j < 2; ++j) {
    int dd = (np * 2 + j) * 16 + l16;
    float cs = (float)colsum[bh * 64 + dd];
#pragma unroll
    for (int r = 0; r < 4; ++r) {
      int srow = m0 + mt * 16 + quad * 4 + r;
      float ctx = sc * acc[j][r] + mnv * cs;
      float c8 = clampf(rintf(ctx / a_o), -128.f, 127.f);
      // ctx[b,h,s,dd] flat == view flat index
      ctxq[(size_t)b * 524288 + (size_t)(h * 128 + (srow >> 3)) * 512 + (srow & 7) * 64 + dd] = (int8_t)c8;
    }
  }
}

// ---------------- output projection MFMA ----------------
__global__ __launch_bounds__(256) void k_outg(
    const int8_t* ctxq, const int8_t* signs_o,
    const float* wabs, const float* ao, float* outb) {
  __shared__ __align__(16) __bf16 As[64][AS];
  __shared__ __align__(16) __bf16 Bs[64][AS];
  int n0 = blockIdx.x * 64, f0 = blockIdx.y * 64;
  int t = threadIdx.x;
  int lane = t & 63, w = t >> 6, quad = lane >> 4, l16 = lane & 15;
  int k16 = (t & 3) * 16, mrow = t >> 2;
  floatx4 acc[4];
#pragma unroll
  for (int nt = 0; nt < 4; ++nt) acc[nt] = (floatx4){0.f, 0.f, 0.f, 0.f};
  for (int k0 = 0; k0 < 512; k0 += 64) {
    {
      int4 ra = *(const int4*)&ctxq[(size_t)(n0 + mrow) * 512 + k0 + k16];
      int4 rb = *(const int4*)&signs_o[(size_t)(f0 + mrow) * 512 + k0 + k16];
      unpack16(&As[mrow][k16], ra);
      unpack16(&Bs[mrow][k16], rb);
    }
    __syncthreads();
#pragma unroll
    for (int kh = 0; kh < 64; kh += 32) {
      bf16x8 a = *(const bf16x8*)&As[w * 16 + l16][kh + quad * 8];
#pragma unroll
      for (int nt = 0; nt < 4; ++nt) {
        bf16x8 b = *(const bf16x8*)&Bs[nt * 16 + l16][kh + quad * 8];
        acc[nt] = __builtin_amdgcn_mfma_f32_16x16x32_bf16(a, b, acc[nt], 0, 0, 0);
      }
    }
    __syncthreads();
  }
  float scale = fmaxf(ao[0], EPSQ) * (wabs[3] * (1.0f / 262144.0f));
#pragma unroll
  for (int nt = 0; nt < 4; ++nt)
#pragma unroll
    for (int r = 0; r < 4; ++r)
      outb[(size_t)(n0 + w * 16 + quad * 4 + r) * 512 + f0 + nt * 16 + l16] = scale * acc[nt][r];
}

// ---------------- layernorm(q + out) -> output 0 ----------------
__global__ __launch_bounds__(256) void k_ln(
    const float* q, const float* outb, const float* g, const float* bb, float* out0) {
  __shared__ float red[256];
  int r = blockIdx.x, t = threadIdx.x;
  const float* qp = q + (size_t)r * 512;
  const float* op = outb + (size_t)r * 512;
  float y0 = qp[t] + op[t];
  float y1 = qp[t + 256] + op[t + 256];
  red[t] = y0 + y1; __syncthreads();
  for (int o = 128; o > 0; o >>= 1) { if (t < o) red[t] += red[t + o]; __syncthreads(); }
  float mu = red[0] * (1.0f / 512.0f); __syncthreads();
  float d0 = y0 - mu, d1 = y1 - mu;
  red[t] = d0 * d0 + d1 * d1; __syncthreads();
  for (int o = 128; o > 0; o >>= 1) { if (t < o) red[t] += red[t + o]; __syncthreads(); }
  float var = red[0] * (1.0f / 512.0f);
  float den = sqrtf(var + 1e-5f);
  out0[(size_t)r * 512 + t]       = d0 / den * g[t] + bb[t];
  out0[(size_t)r * 512 + t + 256] = d1 / den * g[t + 256] + bb[t + 256];
}

extern "C" void kernel_launch(void* const* d_in, const int* in_sizes, int n_in,
                              void* d_out, int out_size, void* d_ws, size_t ws_size,
                              hipStream_t stream) {
  const float* q   = (const float*)d_in[0];
  const float* k   = (const float*)d_in[1];
  const float* v   = (const float*)d_in[2];
  // d_in[3] = mask (int32) — structurally unused by the reference
  const float* Wq  = (const float*)d_in[4];
  const float* Wk  = (const float*)d_in[5];
  const float* Wv  = (const float*)d_in[6];
  const float* Wo  = (const float*)d_in[7];
  const float* bq  = (const float*)d_in[8];
  const float* bk  = (const float*)d_in[9];
  const float* bv  = (const float*)d_in[10];
  const float* lng = (const float*)d_in[11];
  const float* lnb = (const float*)d_in[12];
  const float* aq  = (const float*)d_in[13];
  const float* ak  = (const float*)d_in[14];
  const float* av  = (const float*)d_in[15];
  const float* acq = (const float*)d_in[16];
  const float* ack = (const float*)d_in[17];
  const float* acv = (const float*)d_in[18];
  const float* aca = (const float*)d_in[19];
  const float* ao  = (const float*)d_in[20];

  char* ws = (char*)d_ws;
  float* wsum   = (float*)(ws + O_WSUM);
  float* wabs   = (float*)(ws + O_WABS);
  float* mnf    = (float*)(ws + O_MN);
  int*   colsum = (int*)(ws + O_COLSUM);
  int8_t* signs = (int8_t*)(ws + O_SIGNS);
  int8_t* kqb   = (int8_t*)(ws + O_KQ);
  int8_t* kkb   = (int8_t*)(ws + O_KK);
  int8_t* kvb   = (int8_t*)(ws + O_KV);
  int8_t* vtb   = (int8_t*)(ws + O_VT);
  float* rmax   = (float*)(ws + O_RMAX);
  float* rsum   = (float*)(ws + O_RSUM);
  float* rcand  = (float*)(ws + O_RCAND);
  int8_t* ctxq  = (int8_t*)(ws + O_CTXQ);
  float* outb   = (float*)(ws + O_OUTB);

  float* out0   = (float*)d_out;
  float* scores = (float*)d_out + OUT0N;

  k_init<<<1, 64, 0, stream>>>(wsum, wabs);
  k_wstats<<<256, 256, 0, stream>>>(Wq, Wk, Wv, Wo, wsum, wabs);
  k_sign<<<4096, 256, 0, stream>>>(Wq, Wk, Wv, Wo, wsum, signs);
  k_proj<<<dim3(64, 8, 3), 256, 0, stream>>>(q, k, v, bq, bk, bv, aq, ak, av,
                                             acq, ack, acv, signs, wabs, kqb, kkb, kvb);
  k_vt<<<32, 256, 0, stream>>>(kvb, vtb, colsum);
  k_qks<<<dim3(16, 32), 256, 0, stream>>>(kqb, kkb, acq, ack, scores, rmax, rsum, rcand);
  k_minred<<<1, 1024, 0, stream>>>(rcand, mnf);
  k_pv<<<dim3(32, 32), 256, 0, stream>>>(scores, rmax, rsum, mnf, colsum, vtb,
                                         aca, acv, ao, ctxq);
  k_outg<<<dim3(64, 8), 256, 0, stream>>>(ctxq, signs + 3 * WELEM, wabs, ao, outb);
  k_ln<<<4096, 256, 0, stream>>>(q, outb, lng, lnb, out0);
}

// Round 5
// 378.533 us; speedup vs baseline: 3.4302x; 1.1016x over previous
//
#include <hip/hip_runtime.h>
#include <math.h>
#include <stdint.h>

#define EPSQ 1e-5f
#define WELEM 262144          // 512*512
#define OUT0N 2097152         // 4*1024*512

// ---- workspace byte offsets (all level tensors now bf16) ----
#define O_WSUM   0                        // float[4]  sum(W)
#define O_WABS   16                       // float[4]  sum|W|
#define O_MN     32                       // float     global min(attn)
#define O_COLSUM 64                       // float[2048] colsum of V-levels per (bh,dd)
#define O_WSIGNS 16384                    // bf16[4*262144]  (2 MB)
#define O_KQ     (O_WSIGNS + 8*WELEM)     // bf16[32*1024*64] (4 MB)
#define O_CTXQ   O_KQ                     // bf16 ctx levels, view layout (overlays kq: disjoint lifetime)
#define O_KK     (O_KQ + 4194304)         // bf16 (4 MB)
#define O_VT     (O_KK + 4194304)         // bf16[32][64][1024] V transposed (4 MB)
#define O_RMAX   (O_VT + 4194304)         // float[32768]
#define O_RSUM   (O_RMAX + 131072)        // float[32768]
#define O_OUTB   (O_RSUM + 131072)        // float[2097152] out before LN (8 MB)
#define O_RCAND  O_OUTB                   // float[32768] overlays outb (disjoint lifetime)

#define AS 72  // LDS row stride in bf16 elems: 144 B, 16B-aligned, conflict-benign

typedef __bf16 bf16x8 __attribute__((ext_vector_type(8)));
typedef __bf16 bf16x4 __attribute__((ext_vector_type(4)));
typedef float  floatx4 __attribute__((ext_vector_type(4)));

__device__ __forceinline__ float clampf(float x, float lo, float hi) {
  return fminf(fmaxf(x, lo), hi);
}

// ---------------- init ----------------
__global__ void k_init(float* wsum, float* wabs, float* colsum) {
  int t = threadIdx.x;
  if (t < 4) { wsum[t] = 0.f; wabs[t] = 0.f; }
  for (int i = t; i < 2048; i += 256) colsum[i] = 0.f;
}

// ---------------- weight stats ----------------
__global__ void k_wstats(const float* Wq, const float* Wk, const float* Wv, const float* Wo,
                         float* wsum, float* wabs) {
  __shared__ float s1[256], s2[256];
  int w = blockIdx.x >> 6;
  const float* W = (w == 0) ? Wq : (w == 1) ? Wk : (w == 2) ? Wv : Wo;
  int base = (blockIdx.x & 63) * 4096;
  float s = 0.f, sa = 0.f;
  for (int i = threadIdx.x; i < 4096; i += 256) {
    float x = W[base + i];
    s += x; sa += fabsf(x);
  }
  s1[threadIdx.x] = s; s2[threadIdx.x] = sa; __syncthreads();
  for (int o = 128; o > 0; o >>= 1) {
    if (threadIdx.x < o) { s1[threadIdx.x] += s1[threadIdx.x + o]; s2[threadIdx.x] += s2[threadIdx.x + o]; }
    __syncthreads();
  }
  if (threadIdx.x == 0) { atomicAdd(&wsum[w], s1[0]); atomicAdd(&wabs[w], s2[0]); }
}

// ---------------- binarize -> bf16 signs ----------------
__global__ void k_sign(const float* Wq, const float* Wk, const float* Wv, const float* Wo,
                       const float* wsum, __bf16* wsigns) {
  int idx = blockIdx.x * 256 + threadIdx.x;
  int w = idx >> 18;
  int pos = idx & (WELEM - 1);
  const float* W = (w == 0) ? Wq : (w == 1) ? Wk : (w == 2) ? Wv : Wo;
  float e = wsum[w] * (1.0f / 262144.0f);
  float x = W[pos];
  wsigns[idx] = (__bf16)(float)((x > e) - (x < e));
}

// ---- projection: MFMA int-exact bf16 GEMM + head quant -> bf16 levels ----
// z==2 (V) writes transposed layout directly + float colsum atomics; no k_vt needed.
__global__ __launch_bounds__(256) void k_proj(
    const float* q, const float* kin, const float* vin,
    const float* bq, const float* bk, const float* bv,
    const float* aq, const float* ak, const float* av,
    const float* acq, const float* ack, const float* acv,
    const __bf16* wsigns, const float* wabs,
    __bf16* kqo, __bf16* kko, __bf16* vto, float* colsum) {
  __shared__ __align__(16) __bf16 As[64][AS];
  __shared__ __align__(16) __bf16 Bs[64][AS];
  int z = blockIdx.z;
  const float* X    = (z == 0) ? q   : (z == 1) ? kin : vin;
  const float* bias = (z == 0) ? bq  : (z == 1) ? bk  : bv;
  const float* aip  = (z == 0) ? aq  : (z == 1) ? ak  : av;
  const float* ahp  = (z == 0) ? acq : (z == 1) ? ack : acv;
  float a_in = fmaxf(aip[0], EPSQ);
  float a_hd = fmaxf(ahp[0], EPSQ);
  float m_w  = wabs[z] * (1.0f / 262144.0f);
  const __bf16* S = wsigns + (size_t)z * WELEM;

  int n0 = blockIdx.x * 64;
  int f0 = blockIdx.y * 64;
  int t = threadIdx.x;
  int lane = t & 63, w = t >> 6, quad = lane >> 4, l16 = lane & 15;
  int c4 = (t & 15) * 4, mb = t >> 4;          // A-staging coords
  int e16 = (t & 3) * 16, mrow = t >> 2;       // B-staging coords
  floatx4 acc[4];
#pragma unroll
  for (int nt = 0; nt < 4; ++nt) acc[nt] = (floatx4){0.f, 0.f, 0.f, 0.f};

  for (int k0 = 0; k0 < 512; k0 += 64) {
#pragma unroll
    for (int j = 0; j < 4; ++j) {             // A: fp32 x4 -> quant levels
      int m = mb + j * 16;
      float4 x = *(const float4*)&X[(size_t)(n0 + m) * 512 + k0 + c4];
      bf16x4 av = { (__bf16)clampf(rintf(x.x / a_in), -8.f, 7.f),
                    (__bf16)clampf(rintf(x.y / a_in), -8.f, 7.f),
                    (__bf16)clampf(rintf(x.z / a_in), -8.f, 7.f),
                    (__bf16)clampf(rintf(x.w / a_in), -8.f, 7.f) };
      *(bf16x4*)&As[m][c4] = av;
    }
    {                                          // B: bf16 sign copy (no cvt)
      const __bf16* src = &S[(size_t)(f0 + mrow) * 512 + k0 + e16];
      *(bf16x8*)&Bs[mrow][e16]     = *(const bf16x8*)src;
      *(bf16x8*)&Bs[mrow][e16 + 8] = *(const bf16x8*)(src + 8);
    }
    __syncthreads();
#pragma unroll
    for (int kh = 0; kh < 64; kh += 32) {
      bf16x8 a = *(const bf16x8*)&As[w * 16 + l16][kh + quad * 8];
#pragma unroll
      for (int nt = 0; nt < 4; ++nt) {
        bf16x8 b = *(const bf16x8*)&Bs[nt * 16 + l16][kh + quad * 8];
        acc[nt] = __builtin_amdgcn_mfma_f32_16x16x32_bf16(a, b, acc[nt], 0, 0, 0);
      }
    }
    __syncthreads();
  }
  float s_am = a_in * m_w;
  if (z != 2) {
    __bf16* outp = (z == 0) ? kqo : kko;
#pragma unroll
    for (int nt = 0; nt < 4; ++nt) {
      int f = f0 + nt * 16 + l16;
      int h = f >> 6, dd = f & 63;
      float bia = bias[f];
#pragma unroll
      for (int r = 0; r < 4; ++r) {
        int n = n0 + w * 16 + quad * 4 + r;
        int b = n >> 10, srow = n & 1023;
        float P = s_am * acc[nt][r] + bia;
        float hq = clampf(rintf(P / a_hd), -8.f, 7.f);
        outp[(size_t)((b * 8 + h) * 1024 + srow) * 64 + dd] = (__bf16)hq;
      }
    }
  } else {
    int b = n0 >> 10;                    // 64-row strip never crosses a batch boundary
    int srow0 = (n0 & 1023) + w * 16 + quad * 4;
#pragma unroll
    for (int nt = 0; nt < 4; ++nt) {
      int f = f0 + nt * 16 + l16;
      int h = f >> 6, dd = f & 63;
      int bh = b * 8 + h;
      float bia = bias[f];
      float part = 0.f;
      bf16x4 pack;
#pragma unroll
      for (int r = 0; r < 4; ++r) {
        float P = s_am * acc[nt][r] + bia;
        float hq = clampf(rintf(P / a_hd), -8.f, 7.f);
        pack[r] = (__bf16)hq;
        part += hq;
      }
      *(bf16x4*)&vto[((size_t)bh * 64 + dd) * 1024 + srow0] = pack;
      atomicAdd(&colsum[bh * 64 + dd], part);   // integer-valued floats: exact
    }
  }
}

// ------- fused QK^T + online row stats: one block = 64 rows x all 1024 cols -------
__global__ __launch_bounds__(256) void k_qks(
    const __bf16* kq, const __bf16* kkv,
    const float* acq, const float* ack,
    float* scores, float* rmax, float* rsum, float* rcand) {
  __shared__ __align__(16) __bf16 As[64][AS];
  __shared__ __align__(16) __bf16 Bs[64][AS];
  int bh = blockIdx.y;
  int q0 = blockIdx.x * 64;
  const __bf16* A  = kq  + (size_t)bh * 65536;
  const __bf16* Bp = kkv + (size_t)bh * 65536;
  float* Sp = scores + ((size_t)bh * 1024 + q0) * 1024;
  int t = threadIdx.x;
  int lane = t & 63, w = t >> 6, quad = lane >> 4, l16 = lane & 15;
  int e16 = (t & 3) * 16, mrow = t >> 2;
  float sc = fmaxf(acq[0], EPSQ) * fmaxf(ack[0], EPSQ) * 0.125f;  // /sqrt(64)

  {  // stage A (64 rows x 64 d) once — pure bf16 copy
    const __bf16* src = &A[(q0 + mrow) * 64 + e16];
    *(bf16x8*)&As[mrow][e16]     = *(const bf16x8*)src;
    *(bf16x8*)&As[mrow][e16 + 8] = *(const bf16x8*)(src + 8);
  }
  float m_run[4], l_run[4], mn_run[4];
#pragma unroll
  for (int rr = 0; rr < 4; ++rr) { m_run[rr] = -INFINITY; l_run[rr] = 0.f; mn_run[rr] = INFINITY; }

  for (int ct = 0; ct < 16; ++ct) {
    __syncthreads();  // covers A-stage (ct=0) and prior-tile B reads (ct>0)
    {
      const __bf16* src = &Bp[(ct * 64 + mrow) * 64 + e16];
      *(bf16x8*)&Bs[mrow][e16]     = *(const bf16x8*)src;
      *(bf16x8*)&Bs[mrow][e16 + 8] = *(const bf16x8*)(src + 8);
    }
    __syncthreads();
    floatx4 acc[4];
#pragma unroll
    for (int nt = 0; nt < 4; ++nt) acc[nt] = (floatx4){0.f, 0.f, 0.f, 0.f};
#pragma unroll
    for (int kh = 0; kh < 64; kh += 32) {
      bf16x8 a = *(const bf16x8*)&As[w * 16 + l16][kh + quad * 8];
#pragma unroll
      for (int nt = 0; nt < 4; ++nt) {
        bf16x8 b = *(const bf16x8*)&Bs[nt * 16 + l16][kh + quad * 8];
        acc[nt] = __builtin_amdgcn_mfma_f32_16x16x32_bf16(a, b, acc[nt], 0, 0, 0);
      }
    }
#pragma unroll
    for (int rr = 0; rr < 4; ++rr) {
      int row = w * 16 + quad * 4 + rr;
      float v[4];
#pragma unroll
      for (int nt = 0; nt < 4; ++nt) {
        v[nt] = sc * acc[nt][rr];
        Sp[(size_t)row * 1024 + ct * 64 + nt * 16 + l16] = v[nt];
      }
      float tmax = fmaxf(fmaxf(v[0], v[1]), fmaxf(v[2], v[3]));
      float tmin = fminf(fminf(v[0], v[1]), fminf(v[2], v[3]));
      mn_run[rr] = fminf(mn_run[rr], tmin);
      float mnew = fmaxf(m_run[rr], tmax);
      float s = 0.f;
#pragma unroll
      for (int nt = 0; nt < 4; ++nt) s += expf(v[nt] - mnew);
      l_run[rr] = l_run[rr] * expf(m_run[rr] - mnew) + s;
      m_run[rr] = mnew;
    }
  }
#pragma unroll
  for (int o = 1; o < 16; o <<= 1) {
#pragma unroll
    for (int rr = 0; rr < 4; ++rr) {
      float mo = __shfl_xor(m_run[rr], o);
      float lo = __shfl_xor(l_run[rr], o);
      float mnew = fmaxf(m_run[rr], mo);
      l_run[rr] = l_run[rr] * expf(m_run[rr] - mnew) + lo * expf(mo - mnew);
      m_run[rr] = mnew;
      mn_run[rr] = fminf(mn_run[rr], __shfl_xor(mn_run[rr], o));
    }
  }
  if (l16 == 0) {
#pragma unroll
    for (int rr = 0; rr < 4; ++rr) {
      int r = bh * 1024 + q0 + w * 16 + quad * 4 + rr;
      rmax[r] = m_run[rr];
      rsum[r] = l_run[rr];
      rcand[r] = expf(mn_run[rr] - m_run[rr]) * (1.0f / l_run[rr]);
    }
  }
}

// ---------------- global min of rcand (single block) ----------------
__global__ __launch_bounds__(1024) void k_minred(const float* rcand, float* mnf) {
  __shared__ float red[1024];
  float mn = INFINITY;
  for (int i = threadIdx.x; i < 32768; i += 1024) mn = fminf(mn, rcand[i]);
  red[threadIdx.x] = mn; __syncthreads();
  for (int o = 512; o > 0; o >>= 1) {
    if (threadIdx.x < o) red[threadIdx.x] = fminf(red[threadIdx.x], red[threadIdx.x + o]);
    __syncthreads();
  }
  if (threadIdx.x == 0) mnf[0] = red[0];
}

// ------- softmax + uns4 fused A-staging, PV MFMA, sig8 -> ctxq (view layout) -------
// M=32 tile, 1024 blocks; wave = (mt, nt-pair), 2 acc tiles each
__global__ __launch_bounds__(256) void k_pv(
    const float* scores, const float* rmax, const float* rsum,
    const float* mnf, const float* colsum, const __bf16* vt,
    const float* acattn, const float* acv, const float* ao,
    __bf16* ctxq) {
  __shared__ __align__(16) __bf16 As[32][AS];
  __shared__ __align__(16) __bf16 Bs[64][AS];
  int bh = blockIdx.y;
  int m0 = blockIdx.x * 32;
  float mn = mnf[0];
  float a_att = fmaxf(acattn[0], EPSQ);
  float a_v   = fmaxf(acv[0], EPSQ);
  float a_o   = fmaxf(ao[0], EPSQ);
  const float* Sp  = scores + (size_t)bh * 1048576;
  const __bf16* Vt = vt + (size_t)bh * 65536;
  int t = threadIdx.x;
  int lane = t & 63, w = t >> 6, quad = lane >> 4, l16 = lane & 15;
  int mt = w & 1, np = w >> 1;
  int c4 = (t & 15) * 4, mb = t >> 4;
  int e16 = (t & 3) * 16, mrow = t >> 2;
  float rm[2], rs[2];
#pragma unroll
  for (int j = 0; j < 2; ++j) {
    int r = bh * 1024 + m0 + mb + j * 16;
    rm[j] = rmax[r]; rs[j] = rsum[r];
  }
  floatx4 acc[2];
  acc[0] = (floatx4){0.f, 0.f, 0.f, 0.f};
  acc[1] = (floatx4){0.f, 0.f, 0.f, 0.f};

  for (int k0 = 0; k0 < 1024; k0 += 64) {
#pragma unroll
    for (int j = 0; j < 2; ++j) {   // A: scores -> attn -> uns4 levels
      int m = mb + j * 16;
      float4 s4 = *(const float4*)&Sp[(size_t)(m0 + m) * 1024 + k0 + c4];
      float inv = 1.0f / rs[j];
      bf16x4 av = {
        (__bf16)clampf(rintf((expf(s4.x - rm[j]) * inv - mn) / a_att), 0.f, 15.f),
        (__bf16)clampf(rintf((expf(s4.y - rm[j]) * inv - mn) / a_att), 0.f, 15.f),
        (__bf16)clampf(rintf((expf(s4.z - rm[j]) * inv - mn) / a_att), 0.f, 15.f),
        (__bf16)clampf(rintf((expf(s4.w - rm[j]) * inv - mn) / a_att), 0.f, 15.f) };
      *(bf16x4*)&As[m][c4] = av;
    }
    {                                // B: Vt bf16 copy
      const __bf16* src = &Vt[(size_t)mrow * 1024 + k0 + e16];
      *(bf16x8*)&Bs[mrow][e16]     = *(const bf16x8*)src;
      *(bf16x8*)&Bs[mrow][e16 + 8] = *(const bf16x8*)(src + 8);
    }
    __syncthreads();
#pragma unroll
    for (int kh = 0; kh < 64; kh += 32) {
      bf16x8 a = *(const bf16x8*)&As[mt * 16 + l16][kh + quad * 8];
#pragma unroll
      for (int j = 0; j < 2; ++j) {
        bf16x8 b = *(const bf16x8*)&Bs[(np * 2 + j) * 16 + l16][kh + quad * 8];
        acc[j] = __builtin_amdgcn_mfma_f32_16x16x32_bf16(a, b, acc[j], 0, 0, 0);
      }
    }
    __syncthreads();
  }
  float sc  = a_att * a_v;
  float mnv = mn * a_v;
  int b = bh >> 3, h = bh & 7;
#pragma unroll
  for (int j = 0; j < 2; ++j) {
    int dd = (np * 2 + j) * 16 + l16;
    float cs = colsum[bh * 64 + dd];
#pragma unroll
    for (int r = 0; r < 4; ++r) {
      int srow = m0 + mt * 16 + quad * 4 + r;
      float ctx = sc * acc[j][r] + mnv * cs;
      float c8 = clampf(rintf(ctx / a_o), -128.f, 127.f);
      ctxq[(size_t)b * 524288 + (size_t)(h * 128 + (srow >> 3)) * 512 + (srow & 7) * 64 + dd] = (__bf16)c8;
    }
  }
}

// ---------------- output projection MFMA ----------------
__global__ __launch_bounds__(256) void k_outg(
    const __bf16* ctxq, const __bf16* signs_o,
    const float* wabs, const float* ao, float* outb) {
  __shared__ __align__(16) __bf16 As[64][AS];
  __shared__ __align__(16) __bf16 Bs[64][AS];
  int n0 = blockIdx.x * 64, f0 = blockIdx.y * 64;
  int t = threadIdx.x;
  int lane = t & 63, w = t >> 6, quad = lane >> 4, l16 = lane & 15;
  int e16 = (t & 3) * 16, mrow = t >> 2;
  floatx4 acc[4];
#pragma unroll
  for (int nt = 0; nt < 4; ++nt) acc[nt] = (floatx4){0.f, 0.f, 0.f, 0.f};
  for (int k0 = 0; k0 < 512; k0 += 64) {
    {
      const __bf16* sa = &ctxq[(size_t)(n0 + mrow) * 512 + k0 + e16];
      const __bf16* sb = &signs_o[(size_t)(f0 + mrow) * 512 + k0 + e16];
      *(bf16x8*)&As[mrow][e16]     = *(const bf16x8*)sa;
      *(bf16x8*)&As[mrow][e16 + 8] = *(const bf16x8*)(sa + 8);
      *(bf16x8*)&Bs[mrow][e16]     = *(const bf16x8*)sb;
      *(bf16x8*)&Bs[mrow][e16 + 8] = *(const bf16x8*)(sb + 8);
    }
    __syncthreads();
#pragma unroll
    for (int kh = 0; kh < 64; kh += 32) {
      bf16x8 a = *(const bf16x8*)&As[w * 16 + l16][kh + quad * 8];
#pragma unroll
      for (int nt = 0; nt < 4; ++nt) {
        bf16x8 b = *(const bf16x8*)&Bs[nt * 16 + l16][kh + quad * 8];
        acc[nt] = __builtin_amdgcn_mfma_f32_16x16x32_bf16(a, b, acc[nt], 0, 0, 0);
      }
    }
    __syncthreads();
  }
  float scale = fmaxf(ao[0], EPSQ) * (wabs[3] * (1.0f / 262144.0f));
#pragma unroll
  for (int nt = 0; nt < 4; ++nt)
#pragma unroll
    for (int r = 0; r < 4; ++r)
      outb[(size_t)(n0 + w * 16 + quad * 4 + r) * 512 + f0 + nt * 16 + l16] = scale * acc[nt][r];
}

// ---------------- layernorm(q + out) -> output 0 ----------------
__global__ __launch_bounds__(256) void k_ln(
    const float* q, const float* outb, const float* g, const float* bb, float* out0) {
  __shared__ float red[256];
  int r = blockIdx.x, t = threadIdx.x;
  const float* qp = q + (size_t)r * 512;
  const float* op = outb + (size_t)r * 512;
  float y0 = qp[t] + op[t];
  float y1 = qp[t + 256] + op[t + 256];
  red[t] = y0 + y1; __syncthreads();
  for (int o = 128; o > 0; o >>= 1) { if (t < o) red[t] += red[t + o]; __syncthreads(); }
  float mu = red[0] * (1.0f / 512.0f); __syncthreads();
  float d0 = y0 - mu, d1 = y1 - mu;
  red[t] = d0 * d0 + d1 * d1; __syncthreads();
  for (int o = 128; o > 0; o >>= 1) { if (t < o) red[t] += red[t + o]; __syncthreads(); }
  float var = red[0] * (1.0f / 512.0f);
  float den = sqrtf(var + 1e-5f);
  out0[(size_t)r * 512 + t]       = d0 / den * g[t] + bb[t];
  out0[(size_t)r * 512 + t + 256] = d1 / den * g[t + 256] + bb[t + 256];
}

extern "C" void kernel_launch(void* const* d_in, const int* in_sizes, int n_in,
                              void* d_out, int out_size, void* d_ws, size_t ws_size,
                              hipStream_t stream) {
  const float* q   = (const float*)d_in[0];
  const float* k   = (const float*)d_in[1];
  const float* v   = (const float*)d_in[2];
  // d_in[3] = mask (int32) — structurally unused by the reference
  const float* Wq  = (const float*)d_in[4];
  const float* Wk  = (const float*)d_in[5];
  const float* Wv  = (const float*)d_in[6];
  const float* Wo  = (const float*)d_in[7];
  const float* bq  = (const float*)d_in[8];
  const float* bk  = (const float*)d_in[9];
  const float* bv  = (const float*)d_in[10];
  const float* lng = (const float*)d_in[11];
  const float* lnb = (const float*)d_in[12];
  const float* aq  = (const float*)d_in[13];
  const float* ak  = (const float*)d_in[14];
  const float* av  = (const float*)d_in[15];
  const float* acq = (const float*)d_in[16];
  const float* ack = (const float*)d_in[17];
  const float* acv = (const float*)d_in[18];
  const float* aca = (const float*)d_in[19];
  const float* ao  = (const float*)d_in[20];

  char* ws = (char*)d_ws;
  float*  wsum   = (float*)(ws + O_WSUM);
  float*  wabs   = (float*)(ws + O_WABS);
  float*  mnf    = (float*)(ws + O_MN);
  float*  colsum = (float*)(ws + O_COLSUM);
  __bf16* wsigns = (__bf16*)(ws + O_WSIGNS);
  __bf16* kqb    = (__bf16*)(ws + O_KQ);
  __bf16* kkb    = (__bf16*)(ws + O_KK);
  __bf16* vtb    = (__bf16*)(ws + O_VT);
  float*  rmax   = (float*)(ws + O_RMAX);
  float*  rsum   = (float*)(ws + O_RSUM);
  float*  rcand  = (float*)(ws + O_RCAND);
  __bf16* ctxq   = (__bf16*)(ws + O_CTXQ);
  float*  outb   = (float*)(ws + O_OUTB);

  float* out0   = (float*)d_out;
  float* scores = (float*)d_out + OUT0N;

  k_init<<<1, 256, 0, stream>>>(wsum, wabs, colsum);
  k_wstats<<<256, 256, 0, stream>>>(Wq, Wk, Wv, Wo, wsum, wabs);
  k_sign<<<4096, 256, 0, stream>>>(Wq, Wk, Wv, Wo, wsum, wsigns);
  k_proj<<<dim3(64, 8, 3), 256, 0, stream>>>(q, k, v, bq, bk, bv, aq, ak, av,
                                             acq, ack, acv, wsigns, wabs,
                                             kqb, kkb, vtb, colsum);
  k_qks<<<dim3(16, 32), 256, 0, stream>>>(kqb, kkb, acq, ack, scores, rmax, rsum, rcand);
  k_minred<<<1, 1024, 0, stream>>>(rcand, mnf);
  k_pv<<<dim3(32, 32), 256, 0, stream>>>(scores, rmax, rsum, mnf, colsum, vtb,
                                         aca, acv, ao, ctxq);
  k_outg<<<dim3(64, 8), 256, 0, stream>>>(ctxq, wsigns + 3 * WELEM, wabs, ao, outb);
  k_ln<<<4096, 256, 0, stream>>>(q, outb, lng, lnb, out0);
}

// Round 6
// 346.843 us; speedup vs baseline: 3.7436x; 1.0914x over previous
//
#include <hip/hip_runtime.h>
#include <math.h>
#include <stdint.h>

#define EPSQ 1e-5f
#define WELEM 262144          // 512*512
#define OUT0N 2097152         // 4*1024*512

// ---- workspace byte offsets (all level tensors bf16) ----
#define O_WSUM   0                        // float[4]  sum(W)
#define O_WABS   16                       // float[4]  sum|W|
#define O_MN     32                       // float     global min(attn)
#define O_COLSUM 64                       // float[2048] colsum of V-levels per (bh,dd)
#define O_WSIGNS 16384                    // bf16[4*262144] (2 MB)
#define O_QLV    (O_WSIGNS + 8*WELEM)     // bf16[4096*512] q levels (4 MB)
#define O_CTXQ   O_QLV                    // bf16 ctx levels (overlays qlv: disjoint lifetime)
#define O_KLV    (O_QLV + 4194304)        // bf16 k levels
#define O_VLV    (O_KLV + 4194304)        // bf16 v levels
#define O_KQ     (O_VLV + 4194304)        // bf16[32*1024*64] per-head q levels
#define O_KK     (O_KQ + 4194304)
#define O_VT     (O_KK + 4194304)         // bf16[32][64][1024] V transposed
#define O_RMAX   (O_VT + 4194304)         // float[32768]
#define O_RSUM   (O_RMAX + 131072)        // float[32768]
#define O_OUTB   (O_RSUM + 131072)        // float[2097152] out before LN (8 MB)
#define O_RCAND  O_OUTB                   // float[32768] overlays outb (disjoint lifetime)

#define AS 72  // LDS row stride in bf16 elems: 144 B, 16B-aligned, conflict-benign

typedef __bf16 bf16x8 __attribute__((ext_vector_type(8)));
typedef __bf16 bf16x4 __attribute__((ext_vector_type(4)));
typedef float  floatx4 __attribute__((ext_vector_type(4)));

struct pre2 { bf16x8 lo, hi; };
__device__ __forceinline__ pre2 ldb16(const __bf16* p) {
  pre2 r; r.lo = *(const bf16x8*)p; r.hi = *(const bf16x8*)(p + 8); return r;
}
__device__ __forceinline__ void stb16(__bf16* p, pre2 r) {
  *(bf16x8*)p = r.lo; *(bf16x8*)(p + 8) = r.hi;
}

__device__ __forceinline__ float clampf(float x, float lo, float hi) {
  return fminf(fmaxf(x, lo), hi);
}

// ---------------- init ----------------
__global__ void k_init(float* wsum, float* wabs, float* colsum) {
  int t = threadIdx.x;
  if (t < 4) { wsum[t] = 0.f; wabs[t] = 0.f; }
  for (int i = t; i < 2048; i += 256) colsum[i] = 0.f;
}

// ---------------- weight stats ----------------
__global__ void k_wstats(const float* Wq, const float* Wk, const float* Wv, const float* Wo,
                         float* wsum, float* wabs) {
  __shared__ float s1[256], s2[256];
  int w = blockIdx.x >> 6;
  const float* W = (w == 0) ? Wq : (w == 1) ? Wk : (w == 2) ? Wv : Wo;
  int base = (blockIdx.x & 63) * 4096;
  float s = 0.f, sa = 0.f;
  for (int i = threadIdx.x; i < 4096; i += 256) {
    float x = W[base + i];
    s += x; sa += fabsf(x);
  }
  s1[threadIdx.x] = s; s2[threadIdx.x] = sa; __syncthreads();
  for (int o = 128; o > 0; o >>= 1) {
    if (threadIdx.x < o) { s1[threadIdx.x] += s1[threadIdx.x + o]; s2[threadIdx.x] += s2[threadIdx.x + o]; }
    __syncthreads();
  }
  if (threadIdx.x == 0) { atomicAdd(&wsum[w], s1[0]); atomicAdd(&wabs[w], s2[0]); }
}

// ---------------- binarize -> bf16 signs ----------------
__global__ void k_sign(const float* Wq, const float* Wk, const float* Wv, const float* Wo,
                       const float* wsum, __bf16* wsigns) {
  int idx = blockIdx.x * 256 + threadIdx.x;
  int w = idx >> 18;
  int pos = idx & (WELEM - 1);
  const float* W = (w == 0) ? Wq : (w == 1) ? Wk : (w == 2) ? Wv : Wo;
  float e = wsum[w] * (1.0f / 262144.0f);
  float x = W[pos];
  wsigns[idx] = (__bf16)(float)((x > e) - (x < e));
}

// ---------------- pre-quantize activations: fp32 -> bf16 levels ----------------
__global__ __launch_bounds__(256) void k_qx(
    const float* q, const float* kin, const float* vin,
    const float* aq, const float* ak, const float* av,
    __bf16* qlv, __bf16* klv, __bf16* vlv) {
  int z = blockIdx.y;
  const float* X = (z == 0) ? q : (z == 1) ? kin : vin;
  const float* ap = (z == 0) ? aq : (z == 1) ? ak : av;
  __bf16* O = (z == 0) ? qlv : (z == 1) ? klv : vlv;
  float a = fmaxf(ap[0], EPSQ);
  size_t i = ((size_t)blockIdx.x * 256 + threadIdx.x) * 8;
  float4 x0 = *(const float4*)&X[i];
  float4 x1 = *(const float4*)&X[i + 4];
  bf16x8 o = { (__bf16)clampf(rintf(x0.x / a), -8.f, 7.f),
               (__bf16)clampf(rintf(x0.y / a), -8.f, 7.f),
               (__bf16)clampf(rintf(x0.z / a), -8.f, 7.f),
               (__bf16)clampf(rintf(x0.w / a), -8.f, 7.f),
               (__bf16)clampf(rintf(x1.x / a), -8.f, 7.f),
               (__bf16)clampf(rintf(x1.y / a), -8.f, 7.f),
               (__bf16)clampf(rintf(x1.z / a), -8.f, 7.f),
               (__bf16)clampf(rintf(x1.w / a), -8.f, 7.f) };
  *(bf16x8*)&O[i] = o;
}

// ---- projection: pipelined bf16 MFMA GEMM + head quant -> bf16 levels ----
// z==2 (V) writes transposed layout directly + float colsum atomics.
__global__ __launch_bounds__(256) void k_proj(
    const __bf16* qlv, const __bf16* klv, const __bf16* vlv,
    const float* bq, const float* bk, const float* bv,
    const float* aq, const float* ak, const float* av,
    const float* acq, const float* ack, const float* acv,
    const __bf16* wsigns, const float* wabs,
    __bf16* kqo, __bf16* kko, __bf16* vto, float* colsum) {
  __shared__ __align__(16) __bf16 As[64][AS];
  __shared__ __align__(16) __bf16 Bs[64][AS];
  int z = blockIdx.z;
  const __bf16* X   = (z == 0) ? qlv : (z == 1) ? klv : vlv;
  const float* bias = (z == 0) ? bq  : (z == 1) ? bk  : bv;
  const float* aip  = (z == 0) ? aq  : (z == 1) ? ak  : av;
  const float* ahp  = (z == 0) ? acq : (z == 1) ? ack : acv;
  float a_in = fmaxf(aip[0], EPSQ);
  float a_hd = fmaxf(ahp[0], EPSQ);
  float m_w  = wabs[z] * (1.0f / 262144.0f);
  const __bf16* S = wsigns + (size_t)z * WELEM;

  int n0 = blockIdx.x * 64;
  int f0 = blockIdx.y * 64;
  int t = threadIdx.x;
  int lane = t & 63, w = t >> 6, quad = lane >> 4, l16 = lane & 15;
  int e16 = (t & 3) * 16, mrow = t >> 2;
  const __bf16* ap = &X[(size_t)(n0 + mrow) * 512 + e16];
  const __bf16* bp = &S[(size_t)(f0 + mrow) * 512 + e16];
  floatx4 acc[4];
#pragma unroll
  for (int nt = 0; nt < 4; ++nt) acc[nt] = (floatx4){0.f, 0.f, 0.f, 0.f};

  pre2 pa = ldb16(ap), pb = ldb16(bp);
  for (int k0 = 0; k0 < 512; k0 += 64) {
    if (k0) __syncthreads();
    stb16(&As[mrow][e16], pa);
    stb16(&Bs[mrow][e16], pb);
    if (k0 + 64 < 512) { pa = ldb16(ap + k0 + 64); pb = ldb16(bp + k0 + 64); }
    __syncthreads();
#pragma unroll
    for (int kh = 0; kh < 64; kh += 32) {
      bf16x8 a = *(const bf16x8*)&As[w * 16 + l16][kh + quad * 8];
#pragma unroll
      for (int nt = 0; nt < 4; ++nt) {
        bf16x8 b = *(const bf16x8*)&Bs[nt * 16 + l16][kh + quad * 8];
        acc[nt] = __builtin_amdgcn_mfma_f32_16x16x32_bf16(a, b, acc[nt], 0, 0, 0);
      }
    }
  }
  float s_am = a_in * m_w;
  if (z != 2) {
    __bf16* outp = (z == 0) ? kqo : kko;
#pragma unroll
    for (int nt = 0; nt < 4; ++nt) {
      int f = f0 + nt * 16 + l16;
      int h = f >> 6, dd = f & 63;
      float bia = bias[f];
#pragma unroll
      for (int r = 0; r < 4; ++r) {
        int n = n0 + w * 16 + quad * 4 + r;
        int b = n >> 10, srow = n & 1023;
        float P = s_am * acc[nt][r] + bia;
        float hq = clampf(rintf(P / a_hd), -8.f, 7.f);
        outp[(size_t)((b * 8 + h) * 1024 + srow) * 64 + dd] = (__bf16)hq;
      }
    }
  } else {
    int b = n0 >> 10;                    // 64-row strip never crosses a batch boundary
    int srow0 = (n0 & 1023) + w * 16 + quad * 4;
#pragma unroll
    for (int nt = 0; nt < 4; ++nt) {
      int f = f0 + nt * 16 + l16;
      int h = f >> 6, dd = f & 63;
      int bh = b * 8 + h;
      float bia = bias[f];
      float part = 0.f;
      bf16x4 pack;
#pragma unroll
      for (int r = 0; r < 4; ++r) {
        float P = s_am * acc[nt][r] + bia;
        float hq = clampf(rintf(P / a_hd), -8.f, 7.f);
        pack[r] = (__bf16)hq;
        part += hq;
      }
      *(bf16x4*)&vto[((size_t)bh * 64 + dd) * 1024 + srow0] = pack;
      atomicAdd(&colsum[bh * 64 + dd], part);   // integer-valued floats: exact
    }
  }
}

// ------- fused QK^T + online row stats, pipelined B tiles -------
__global__ __launch_bounds__(256) void k_qks(
    const __bf16* kq, const __bf16* kkv,
    const float* acq, const float* ack,
    float* scores, float* rmax, float* rsum, float* rcand) {
  __shared__ __align__(16) __bf16 As[64][AS];
  __shared__ __align__(16) __bf16 Bs[64][AS];
  int bh = blockIdx.y;
  int q0 = blockIdx.x * 64;
  const __bf16* A  = kq  + (size_t)bh * 65536;
  const __bf16* Bp = kkv + (size_t)bh * 65536;
  float* Sp = scores + ((size_t)bh * 1024 + q0) * 1024;
  int t = threadIdx.x;
  int lane = t & 63, w = t >> 6, quad = lane >> 4, l16 = lane & 15;
  int e16 = (t & 3) * 16, mrow = t >> 2;
  float sc = fmaxf(acq[0], EPSQ) * fmaxf(ack[0], EPSQ) * 0.125f;  // /sqrt(64)

  stb16(&As[mrow][e16], ldb16(&A[(q0 + mrow) * 64 + e16]));  // stage A once
  float m_run[4], l_run[4], mn_run[4];
#pragma unroll
  for (int rr = 0; rr < 4; ++rr) { m_run[rr] = -INFINITY; l_run[rr] = 0.f; mn_run[rr] = INFINITY; }

  pre2 pb = ldb16(&Bp[mrow * 64 + e16]);
  for (int ct = 0; ct < 16; ++ct) {
    if (ct) __syncthreads();
    stb16(&Bs[mrow][e16], pb);
    if (ct < 15) pb = ldb16(&Bp[((ct + 1) * 64 + mrow) * 64 + e16]);
    __syncthreads();
    floatx4 acc[4];
#pragma unroll
    for (int nt = 0; nt < 4; ++nt) acc[nt] = (floatx4){0.f, 0.f, 0.f, 0.f};
#pragma unroll
    for (int kh = 0; kh < 64; kh += 32) {
      bf16x8 a = *(const bf16x8*)&As[w * 16 + l16][kh + quad * 8];
#pragma unroll
      for (int nt = 0; nt < 4; ++nt) {
        bf16x8 b = *(const bf16x8*)&Bs[nt * 16 + l16][kh + quad * 8];
        acc[nt] = __builtin_amdgcn_mfma_f32_16x16x32_bf16(a, b, acc[nt], 0, 0, 0);
      }
    }
#pragma unroll
    for (int rr = 0; rr < 4; ++rr) {
      int row = w * 16 + quad * 4 + rr;
      float v[4];
#pragma unroll
      for (int nt = 0; nt < 4; ++nt) {
        v[nt] = sc * acc[nt][rr];
        Sp[(size_t)row * 1024 + ct * 64 + nt * 16 + l16] = v[nt];
      }
      float tmax = fmaxf(fmaxf(v[0], v[1]), fmaxf(v[2], v[3]));
      float tmin = fminf(fminf(v[0], v[1]), fminf(v[2], v[3]));
      mn_run[rr] = fminf(mn_run[rr], tmin);
      float mnew = fmaxf(m_run[rr], tmax);
      float s = 0.f;
#pragma unroll
      for (int nt = 0; nt < 4; ++nt) s += expf(v[nt] - mnew);
      l_run[rr] = l_run[rr] * expf(m_run[rr] - mnew) + s;
      m_run[rr] = mnew;
    }
  }
#pragma unroll
  for (int o = 1; o < 16; o <<= 1) {
#pragma unroll
    for (int rr = 0; rr < 4; ++rr) {
      float mo = __shfl_xor(m_run[rr], o);
      float lo = __shfl_xor(l_run[rr], o);
      float mnew = fmaxf(m_run[rr], mo);
      l_run[rr] = l_run[rr] * expf(m_run[rr] - mnew) + lo * expf(mo - mnew);
      m_run[rr] = mnew;
      mn_run[rr] = fminf(mn_run[rr], __shfl_xor(mn_run[rr], o));
    }
  }
  if (l16 == 0) {
#pragma unroll
    for (int rr = 0; rr < 4; ++rr) {
      int r = bh * 1024 + q0 + w * 16 + quad * 4 + rr;
      rmax[r] = m_run[rr];
      rsum[r] = l_run[rr];
      rcand[r] = expf(mn_run[rr] - m_run[rr]) * (1.0f / l_run[rr]);
    }
  }
}

// ---------------- global min of rcand (single block) ----------------
__global__ __launch_bounds__(1024) void k_minred(const float* rcand, float* mnf) {
  __shared__ float red[1024];
  float mn = INFINITY;
  for (int i = threadIdx.x; i < 32768; i += 1024) mn = fminf(mn, rcand[i]);
  red[threadIdx.x] = mn; __syncthreads();
  for (int o = 512; o > 0; o >>= 1) {
    if (threadIdx.x < o) red[threadIdx.x] = fminf(red[threadIdx.x], red[threadIdx.x + o]);
    __syncthreads();
  }
  if (threadIdx.x == 0) mnf[0] = red[0];
}

// ------- softmax + uns4 fused A-staging, pipelined PV MFMA, sig8 -> ctxq -------
__global__ __launch_bounds__(256) void k_pv(
    const float* scores, const float* rmax, const float* rsum,
    const float* mnf, const float* colsum, const __bf16* vt,
    const float* acattn, const float* acv, const float* ao,
    __bf16* ctxq) {
  __shared__ __align__(16) __bf16 As[32][AS];
  __shared__ __align__(16) __bf16 Bs[64][AS];
  int bh = blockIdx.y;
  int m0 = blockIdx.x * 32;
  float mn = mnf[0];
  float a_att = fmaxf(acattn[0], EPSQ);
  float a_v   = fmaxf(acv[0], EPSQ);
  float a_o   = fmaxf(ao[0], EPSQ);
  const float* Sp  = scores + (size_t)bh * 1048576;
  const __bf16* Vt = vt + (size_t)bh * 65536;
  int t = threadIdx.x;
  int lane = t & 63, w = t >> 6, quad = lane >> 4, l16 = lane & 15;
  int mt = w & 1, np = w >> 1;
  int c4 = (t & 15) * 4, mb = t >> 4;
  int e16 = (t & 3) * 16, mrow = t >> 2;
  float rm[2], rs[2];
#pragma unroll
  for (int j = 0; j < 2; ++j) {
    int r = bh * 1024 + m0 + mb + j * 16;
    rm[j] = rmax[r]; rs[j] = rsum[r];
  }
  floatx4 acc[2];
  acc[0] = (floatx4){0.f, 0.f, 0.f, 0.f};
  acc[1] = (floatx4){0.f, 0.f, 0.f, 0.f};

  float4 ps[2];
#pragma unroll
  for (int j = 0; j < 2; ++j)
    ps[j] = *(const float4*)&Sp[(size_t)(m0 + mb + j * 16) * 1024 + c4];
  pre2 pvb = ldb16(&Vt[(size_t)mrow * 1024 + e16]);

  for (int k0 = 0; k0 < 1024; k0 += 64) {
    if (k0) __syncthreads();
#pragma unroll
    for (int j = 0; j < 2; ++j) {   // process prefetched scores -> uns4 levels
      float inv = 1.0f / rs[j];
      bf16x4 av = {
        (__bf16)clampf(rintf((expf(ps[j].x - rm[j]) * inv - mn) / a_att), 0.f, 15.f),
        (__bf16)clampf(rintf((expf(ps[j].y - rm[j]) * inv - mn) / a_att), 0.f, 15.f),
        (__bf16)clampf(rintf((expf(ps[j].z - rm[j]) * inv - mn) / a_att), 0.f, 15.f),
        (__bf16)clampf(rintf((expf(ps[j].w - rm[j]) * inv - mn) / a_att), 0.f, 15.f) };
      *(bf16x4*)&As[mb + j * 16][c4] = av;
    }
    stb16(&Bs[mrow][e16], pvb);
    if (k0 + 64 < 1024) {
#pragma unroll
      for (int j = 0; j < 2; ++j)
        ps[j] = *(const float4*)&Sp[(size_t)(m0 + mb + j * 16) * 1024 + k0 + 64 + c4];
      pvb = ldb16(&Vt[(size_t)mrow * 1024 + k0 + 64 + e16]);
    }
    __syncthreads();
#pragma unroll
    for (int kh = 0; kh < 64; kh += 32) {
      bf16x8 a = *(const bf16x8*)&As[mt * 16 + l16][kh + quad * 8];
#pragma unroll
      for (int j = 0; j < 2; ++j) {
        bf16x8 b = *(const bf16x8*)&Bs[(np * 2 + j) * 16 + l16][kh + quad * 8];
        acc[j] = __builtin_amdgcn_mfma_f32_16x16x32_bf16(a, b, acc[j], 0, 0, 0);
      }
    }
  }
  float sc  = a_att * a_v;
  float mnv = mn * a_v;
  int b = bh >> 3, h = bh & 7;
#pragma unroll
  for (int j = 0; j < 2; ++j) {
    int dd = (np * 2 + j) * 16 + l16;
    float cs = colsum[bh * 64 + dd];
#pragma unroll
    for (int r = 0; r < 4; ++r) {
      int srow = m0 + mt * 16 + quad * 4 + r;
      float ctx = sc * acc[j][r] + mnv * cs;
      float c8 = clampf(rintf(ctx / a_o), -128.f, 127.f);
      ctxq[(size_t)b * 524288 + (size_t)(h * 128 + (srow >> 3)) * 512 + (srow & 7) * 64 + dd] = (__bf16)c8;
    }
  }
}

// ---------------- output projection MFMA, pipelined ----------------
__global__ __launch_bounds__(256) void k_outg(
    const __bf16* ctxq, const __bf16* signs_o,
    const float* wabs, const float* ao, float* outb) {
  __shared__ __align__(16) __bf16 As[64][AS];
  __shared__ __align__(16) __bf16 Bs[64][AS];
  int n0 = blockIdx.x * 64, f0 = blockIdx.y * 64;
  int t = threadIdx.x;
  int lane = t & 63, w = t >> 6, quad = lane >> 4, l16 = lane & 15;
  int e16 = (t & 3) * 16, mrow = t >> 2;
  const __bf16* ap = &ctxq[(size_t)(n0 + mrow) * 512 + e16];
  const __bf16* bp = &signs_o[(size_t)(f0 + mrow) * 512 + e16];
  floatx4 acc[4];
#pragma unroll
  for (int nt = 0; nt < 4; ++nt) acc[nt] = (floatx4){0.f, 0.f, 0.f, 0.f};
  pre2 pa = ldb16(ap), pb = ldb16(bp);
  for (int k0 = 0; k0 < 512; k0 += 64) {
    if (k0) __syncthreads();
    stb16(&As[mrow][e16], pa);
    stb16(&Bs[mrow][e16], pb);
    if (k0 + 64 < 512) { pa = ldb16(ap + k0 + 64); pb = ldb16(bp + k0 + 64); }
    __syncthreads();
#pragma unroll
    for (int kh = 0; kh < 64; kh += 32) {
      bf16x8 a = *(const bf16x8*)&As[w * 16 + l16][kh + quad * 8];
#pragma unroll
      for (int nt = 0; nt < 4; ++nt) {
        bf16x8 b = *(const bf16x8*)&Bs[nt * 16 + l16][kh + quad * 8];
        acc[nt] = __builtin_amdgcn_mfma_f32_16x16x32_bf16(a, b, acc[nt], 0, 0, 0);
      }
    }
  }
  float scale = fmaxf(ao[0], EPSQ) * (wabs[3] * (1.0f / 262144.0f));
#pragma unroll
  for (int nt = 0; nt < 4; ++nt)
#pragma unroll
    for (int r = 0; r < 4; ++r)
      outb[(size_t)(n0 + w * 16 + quad * 4 + r) * 512 + f0 + nt * 16 + l16] = scale * acc[nt][r];
}

// ---------------- layernorm(q + out) -> output 0 ----------------
__global__ __launch_bounds__(256) void k_ln(
    const float* q, const float* outb, const float* g, const float* bb, float* out0) {
  __shared__ float red[256];
  int r = blockIdx.x, t = threadIdx.x;
  const float* qp = q + (size_t)r * 512;
  const float* op = outb + (size_t)r * 512;
  float y0 = qp[t] + op[t];
  float y1 = qp[t + 256] + op[t + 256];
  red[t] = y0 + y1; __syncthreads();
  for (int o = 128; o > 0; o >>= 1) { if (t < o) red[t] += red[t + o]; __syncthreads(); }
  float mu = red[0] * (1.0f / 512.0f); __syncthreads();
  float d0 = y0 - mu, d1 = y1 - mu;
  red[t] = d0 * d0 + d1 * d1; __syncthreads();
  for (int o = 128; o > 0; o >>= 1) { if (t < o) red[t] += red[t + o]; __syncthreads(); }
  float var = red[0] * (1.0f / 512.0f);
  float den = sqrtf(var + 1e-5f);
  out0[(size_t)r * 512 + t]       = d0 / den * g[t] + bb[t];
  out0[(size_t)r * 512 + t + 256] = d1 / den * g[t + 256] + bb[t + 256];
}

extern "C" void kernel_launch(void* const* d_in, const int* in_sizes, int n_in,
                              void* d_out, int out_size, void* d_ws, size_t ws_size,
                              hipStream_t stream) {
  const float* q   = (const float*)d_in[0];
  const float* k   = (const float*)d_in[1];
  const float* v   = (const float*)d_in[2];
  // d_in[3] = mask (int32) — structurally unused by the reference
  const float* Wq  = (const float*)d_in[4];
  const float* Wk  = (const float*)d_in[5];
  const float* Wv  = (const float*)d_in[6];
  const float* Wo  = (const float*)d_in[7];
  const float* bq  = (const float*)d_in[8];
  const float* bk  = (const float*)d_in[9];
  const float* bv  = (const float*)d_in[10];
  const float* lng = (const float*)d_in[11];
  const float* lnb = (const float*)d_in[12];
  const float* aq  = (const float*)d_in[13];
  const float* ak  = (const float*)d_in[14];
  const float* av  = (const float*)d_in[15];
  const float* acq = (const float*)d_in[16];
  const float* ack = (const float*)d_in[17];
  const float* acv = (const float*)d_in[18];
  const float* aca = (const float*)d_in[19];
  const float* ao  = (const float*)d_in[20];

  char* ws = (char*)d_ws;
  float*  wsum   = (float*)(ws + O_WSUM);
  float*  wabs   = (float*)(ws + O_WABS);
  float*  mnf    = (float*)(ws + O_MN);
  float*  colsum = (float*)(ws + O_COLSUM);
  __bf16* wsigns = (__bf16*)(ws + O_WSIGNS);
  __bf16* qlv    = (__bf16*)(ws + O_QLV);
  __bf16* klv    = (__bf16*)(ws + O_KLV);
  __bf16* vlv    = (__bf16*)(ws + O_VLV);
  __bf16* kqb    = (__bf16*)(ws + O_KQ);
  __bf16* kkb    = (__bf16*)(ws + O_KK);
  __bf16* vtb    = (__bf16*)(ws + O_VT);
  float*  rmax   = (float*)(ws + O_RMAX);
  float*  rsum   = (float*)(ws + O_RSUM);
  float*  rcand  = (float*)(ws + O_RCAND);
  __bf16* ctxq   = (__bf16*)(ws + O_CTXQ);
  float*  outb   = (float*)(ws + O_OUTB);

  float* out0   = (float*)d_out;
  float* scores = (float*)d_out + OUT0N;

  k_init<<<1, 256, 0, stream>>>(wsum, wabs, colsum);
  k_wstats<<<256, 256, 0, stream>>>(Wq, Wk, Wv, Wo, wsum, wabs);
  k_sign<<<4096, 256, 0, stream>>>(Wq, Wk, Wv, Wo, wsum, wsigns);
  k_qx<<<dim3(1024, 3), 256, 0, stream>>>(q, k, v, aq, ak, av, qlv, klv, vlv);
  k_proj<<<dim3(64, 8, 3), 256, 0, stream>>>(qlv, klv, vlv, bq, bk, bv, aq, ak, av,
                                             acq, ack, acv, wsigns, wabs,
                                             kqb, kkb, vtb, colsum);
  k_qks<<<dim3(16, 32), 256, 0, stream>>>(kqb, kkb, acq, ack, scores, rmax, rsum, rcand);
  k_minred<<<1, 1024, 0, stream>>>(rcand, mnf);
  k_pv<<<dim3(32, 32), 256, 0, stream>>>(scores, rmax, rsum, mnf, colsum, vtb,
                                         aca, acv, ao, ctxq);
  k_outg<<<dim3(64, 8), 256, 0, stream>>>(ctxq, wsigns + 3 * WELEM, wabs, ao, outb);
  k_ln<<<4096, 256, 0, stream>>>(q, outb, lng, lnb, out0);
}